// Round 12
// baseline (457.005 us; speedup 1.0000x reference)
//
#include <hip/hip_runtime.h>
#include <cstdint>
#include <cstddef>

#define NN 100000   // nodes
#define NE 1600000  // edges
#define DD 128      // feature dim
#define NG 64       // graphs
#define NB 782      // buckets of 128 nodes
#define GB 1563     // gemm blocks: ceil(NN/64)

#if defined(__has_builtin)
#if __has_builtin(__builtin_amdgcn_cvt_pk_f32_fp8) && __has_builtin(__builtin_amdgcn_cvt_pk_fp8_f32)
#define USE_FP8 1
#endif
#endif
#ifndef USE_FP8
#define USE_FP8 0
#endif

using bf16x8 = __attribute__((ext_vector_type(8))) short;
using f32x4  = __attribute__((ext_vector_type(4))) float;
using f32x2  = __attribute__((ext_vector_type(2))) float;

__device__ __forceinline__ int clampi(int v, int hi) {
    v = v < 0 ? 0 : v;
    return v >= hi ? hi - 1 : v;
}
__device__ __forceinline__ unsigned short f2bf(float f) {
    unsigned int u = __float_as_uint(f);
    u += 0x7fffu + ((u >> 16) & 1u);   // RNE
    return (unsigned short)(u >> 16);
}
__device__ __forceinline__ float bf2f(unsigned short s) {
    return __uint_as_float(((unsigned int)s) << 16);
}
#if USE_FP8
__device__ __forceinline__ unsigned char f2fp8(float v) {
    return (unsigned char)(__builtin_amdgcn_cvt_pk_fp8_f32(v, 0.f, 0, false) & 0xFF);
}
#endif

// ---------------------------------------------------------------------------
// cvtw: weights -> bf16 Wcat3 in FRAGMENT order (coalesced wave B-loads)
// + zero-init bcnt/gcur0/pooled/cnt.
// ---------------------------------------------------------------------------
#define WTOT (3 * 256 * 128)
__global__ void cvtw_kernel(const float* __restrict__ Wl, const float* __restrict__ Wr,
                            unsigned short* __restrict__ Wcat3,
                            int* __restrict__ bcnt, int* __restrict__ gcur0,
                            float* __restrict__ pooled, float* __restrict__ cnt) {
    int t = blockIdx.x * 256 + threadIdx.x;
    if (t < NB) { bcnt[t] = 0; gcur0[t] = 0; }
    if (t < NG * DD) pooled[t] = 0.f;
    if (t < NG) cnt[t] = 0.f;
    if (t < WTOT) {
        int j    = t & 7;
        int lane = (t >> 3) & 63;
        int ks   = (t >> 9) & 3;
        int n    = (t >> 11) & 7;
        int half = (t >> 14) & 1;
        int l    = t >> 15;
        int l15 = lane & 15, lg = lane >> 4;
        int o = n * 16 + l15;
        int k = ks * 32 + lg * 8 + j;
        const float* Wsrc = half ? Wr : Wl;
        Wcat3[t] = f2bf(Wsrc[(size_t)l * 16384 + o * 128 + k]);
    }
}

// ---------------------------------------------------------------------------
// GEMM v4 (validated round 11): [z|u] = h @ [Wl|Wr]^T, z += bl.
// A via XOR-swizzled LDS; B via fragment-ordered coalesced loads; u -> fp8.
// Extra blocks run the CSR bucket histogram (layer-1 co-launch).
// ---------------------------------------------------------------------------
template <bool F32IN>
__global__ __launch_bounds__(256) void gemm4_kernel(
    const void* __restrict__ hin_, const unsigned short* __restrict__ Wf,
    const float* __restrict__ bl, unsigned short* __restrict__ zb,
    unsigned char* __restrict__ ub, const int* __restrict__ dst,
    int* __restrict__ bcnt, int nG) {
    __shared__ unsigned short lA[64 * 128];
    __shared__ unsigned short sstz[64][136];

    if (blockIdx.x >= nG) {   // bcount branch
        int* lcnt = (int*)lA;
        for (int i = threadIdx.x; i < NB; i += 256) lcnt[i] = 0;
        __syncthreads();
        int b = blockIdx.x - nG;
        int e0 = b * 8000;
        int e1 = e0 + 8000; if (e1 > NE) e1 = NE;
        for (int e = e0 + threadIdx.x; e < e1; e += 256)
            atomicAdd(&lcnt[clampi(dst[e], NN) >> 7], 1);
        __syncthreads();
        for (int i = threadIdx.x; i < NB; i += 256)
            if (lcnt[i]) atomicAdd(&bcnt[i], lcnt[i]);
        return;
    }

    const int tid = threadIdx.x;
    const int w = tid >> 6, l = tid & 63;
    const int l15 = l & 15, lg = l >> 4;
    const int n0 = blockIdx.x * 64;

#pragma unroll
    for (int q = 0; q < 4; ++q) {
        int d = (q * 256 + tid) * 16;
        int row = d >> 8;
        int colb = d & 255;
        int srow = n0 + row; srow = srow < NN ? srow : NN - 1;
        bf16x8 v;
        if (F32IN) {
            const float* rp = (const float*)hin_ + (size_t)srow * DD + (colb >> 1);
            const float4 f0 = *(const float4*)rp;
            const float4 f1 = *(const float4*)(rp + 4);
            v[0] = (short)f2bf(f0.x); v[1] = (short)f2bf(f0.y);
            v[2] = (short)f2bf(f0.z); v[3] = (short)f2bf(f0.w);
            v[4] = (short)f2bf(f1.x); v[5] = (short)f2bf(f1.y);
            v[6] = (short)f2bf(f1.z); v[7] = (short)f2bf(f1.w);
        } else {
            v = *(const bf16x8*)((const unsigned short*)hin_ + (size_t)srow * DD + (colb >> 1));
        }
        int sd = d ^ (((d >> 8) & 7) << 4);
        *(bf16x8*)((char*)lA + sd) = v;
    }
    __syncthreads();

    const int half = w >> 1, rt = w & 1;

    bf16x8 a[4][2];
#pragma unroll
    for (int ks = 0; ks < 4; ++ks)
#pragma unroll
        for (int m = 0; m < 2; ++m) {
            int row = rt * 32 + m * 16 + l15;
            int L = row * 256 + ks * 64 + lg * 16;
            int SL = L ^ (((L >> 8) & 7) << 4);
            a[ks][m] = *(const bf16x8*)((char*)lA + SL);
        }

    f32x4 acc[2][8];
#pragma unroll
    for (int m = 0; m < 2; ++m)
#pragma unroll
        for (int n = 0; n < 8; ++n) acc[m][n] = (f32x4){0.f, 0.f, 0.f, 0.f};

    const unsigned short* Wb = Wf + ((size_t)half << 14);
#pragma unroll
    for (int ks = 0; ks < 4; ++ks) {
#pragma unroll
        for (int n = 0; n < 8; ++n) {
            bf16x8 b = *(const bf16x8*)(Wb + (((n << 2) + ks) << 9) + (l << 3));
            acc[0][n] = __builtin_amdgcn_mfma_f32_16x16x32_bf16(a[ks][0], b, acc[0][n], 0, 0, 0);
            acc[1][n] = __builtin_amdgcn_mfma_f32_16x16x32_bf16(a[ks][1], b, acc[1][n], 0, 0, 0);
        }
    }

    __syncthreads();

    if (half == 0) {
        float blv[8];
#pragma unroll
        for (int n = 0; n < 8; ++n) blv[n] = bl[n * 16 + l15];
#pragma unroll
        for (int m = 0; m < 2; ++m)
#pragma unroll
            for (int r = 0; r < 4; ++r) {
                int brow = rt * 32 + m * 16 + lg * 4 + r;
#pragma unroll
                for (int n = 0; n < 8; ++n)
                    sstz[brow][n * 16 + l15] = f2bf(acc[m][n][r] + blv[n]);
            }
#pragma unroll
        for (int p = 0; p < 8; ++p) {
            int brow = rt * 32 + p * 4 + lg;
            int node = n0 + brow;
            bf16x8 vv = *(const bf16x8*)(&sstz[brow][l15 * 8]);
            if (node < NN)
                *(bf16x8*)(zb + (size_t)node * DD + l15 * 8) = vv;
        }
    } else {
#if USE_FP8
        unsigned char* sstu = (unsigned char*)lA;
#pragma unroll
        for (int m = 0; m < 2; ++m)
#pragma unroll
            for (int r = 0; r < 4; ++r) {
                int brow = rt * 32 + m * 16 + lg * 4 + r;
#pragma unroll
                for (int n = 0; n < 8; ++n)
                    sstu[brow * 136 + n * 16 + l15] = f2fp8(acc[m][n][r]);
            }
        __builtin_amdgcn_s_waitcnt(0);
#pragma unroll
        for (int p = 0; p < 8; ++p) {
            int brow = rt * 32 + p * 4 + lg;
            int node = n0 + brow;
            uint2 vv = *(const uint2*)(sstu + brow * 136 + l15 * 8);
            if (node < NN)
                *(uint2*)(ub + (size_t)node * DD + l15 * 8) = vv;
        }
#else
        unsigned short* ub16 = (unsigned short*)ub;
#pragma unroll
        for (int m = 0; m < 2; ++m)
#pragma unroll
            for (int r = 0; r < 4; ++r) {
                int brow = rt * 32 + m * 16 + lg * 4 + r;
                int node = n0 + brow;
                if (node < NN)
#pragma unroll
                    for (int n = 0; n < 8; ++n)
                        ub16[(size_t)node * DD + n * 16 + l15] = f2bf(acc[m][n][r]);
            }
#endif
    }
}

// ---------------------------------------------------------------------------
// CSR build (unchanged)
// ---------------------------------------------------------------------------
__global__ __launch_bounds__(256) void bpart2_kernel(
    const int* __restrict__ src, const int* __restrict__ dst,
    const int* __restrict__ bcnt, int* __restrict__ gcur0,
    int* __restrict__ bstart_g, uint2* __restrict__ stage) {
    __shared__ int bst[NB];
    __shared__ int lcnt[NB];
    __shared__ int partial[256];
    const int t = threadIdx.x;
    int own[4]; int ssum = 0;
#pragma unroll
    for (int q = 0; q < 4; ++q) {
        int idx = t * 4 + q;
        own[q] = (idx < NB) ? bcnt[idx] : 0;
        ssum += own[q];
    }
    partial[t] = ssum;
    __syncthreads();
    for (int d = 1; d < 256; d <<= 1) {
        int v = (t >= d) ? partial[t - d] : 0;
        __syncthreads();
        partial[t] += v;
        __syncthreads();
    }
    int run = partial[t] - ssum;
#pragma unroll
    for (int q = 0; q < 4; ++q) {
        int idx = t * 4 + q;
        if (idx < NB) bst[idx] = run;
        run += own[q];
    }
    if (blockIdx.x == 0) {
#pragma unroll
        for (int q = 0; q < 4; ++q) {
            int idx = t * 4 + q;
            if (idx < NB) bstart_g[idx] = bst[idx];
        }
        if (t == 0) bstart_g[NB] = NE;
    }
    for (int i = t; i < NB; i += 256) lcnt[i] = 0;
    __syncthreads();
    int e0 = blockIdx.x * 8000;
    int e1 = e0 + 8000; if (e1 > NE) e1 = NE;
    for (int e = e0 + t; e < e1; e += 256)
        atomicAdd(&lcnt[clampi(dst[e], NN) >> 7], 1);
    __syncthreads();
    for (int i = t; i < NB; i += 256) {
        int c = lcnt[i];
        if (c) lcnt[i] = bst[i] + atomicAdd(&gcur0[i], c);
    }
    __syncthreads();
    for (int e = e0 + t; e < e1; e += 256) {
        int d = clampi(dst[e], NN);
        int pos = atomicAdd(&lcnt[d >> 7], 1);
        uint2 p; p.x = (unsigned)clampi(src[e], NN); p.y = (unsigned)d;
        stage[pos] = p;
    }
}

__global__ __launch_bounds__(256) void bfill_kernel(
    const uint2* __restrict__ stage, const int* __restrict__ bstart,
    int* __restrict__ row_ptr, int* __restrict__ csr) {
    __shared__ int scnt[128];
    __shared__ int scur[128];
    const int b = blockIdx.x;
    const int t = threadIdx.x;
    const int s0 = bstart[b], s1 = bstart[b + 1];
    const int n0 = b << 7;
    int nend = NN - n0; if (nend > 128) nend = 128;
    if (t < 128) scnt[t] = 0;
    __syncthreads();
    for (int i = s0 + t; i < s1; i += 256)
        atomicAdd(&scnt[stage[i].y & 127], 1);
    __syncthreads();
    int own = (t < 128) ? scnt[t] : 0;
    for (int d = 1; d < 128; d <<= 1) {
        int v = (t < 128 && t >= d) ? scnt[t - d] : 0;
        __syncthreads();
        if (t < 128) scnt[t] += v;
        __syncthreads();
    }
    if (t < 128) {
        int excl = scnt[t] - own;
        scur[t] = excl;
        if (t < nend) row_ptr[n0 + t] = s0 + excl;
    }
    if (b == NB - 1 && t == 0) row_ptr[NN] = NE;
    __syncthreads();
    for (int i = s0 + t; i < s1; i += 256) {
        uint2 p = stage[i];
        int slot = atomicAdd(&scur[p.y & 127], 1);
        csr[s0 + slot] = (int)p.x;
    }
}

// ---------------------------------------------------------------------------
// Pull + combine v3: TWO nodes per wave, fused main/drain/remainder loops so
// both nodes' gather chains overlap (8 rows in flight). 16-lane groups,
// f32x2 pk accumulation. h' = relu(normalize(z + mean(u[src]) + [deg>0]*br)).
// ---------------------------------------------------------------------------
#if USE_FP8
__device__ __forceinline__ void acc_row(f32x2* a2, uint2 v) {
    f32x2 p;
    p = __builtin_amdgcn_cvt_pk_f32_fp8(v.x, false); a2[0] += p;
    p = __builtin_amdgcn_cvt_pk_f32_fp8(v.x, true);  a2[1] += p;
    p = __builtin_amdgcn_cvt_pk_f32_fp8(v.y, false); a2[2] += p;
    p = __builtin_amdgcn_cvt_pk_f32_fp8(v.y, true);  a2[3] += p;
}
#endif

__global__ __launch_bounds__(256) void pullc2_kernel(
    const unsigned char* __restrict__ u, const unsigned short* __restrict__ z,
    const float* __restrict__ br, const int* __restrict__ row_ptr,
    const int* __restrict__ csr, unsigned short* __restrict__ hOut) {
    int w = threadIdx.x >> 6, lane = threadIdx.x & 63;
    int g = lane >> 4, c = lane & 15;
    int nA = blockIdx.x * 8 + w * 2;
    if (nA >= NN) return;
    int nB = nA + 1;
    bool hasB = nB < NN;
    int s0a = row_ptr[nA], s1a = row_ptr[nA + 1];
    int s0b = 0, s1b = 0;
    if (hasB) { s0b = row_ptr[nB], s1b = row_ptr[nB + 1]; }
    int lenA = s1a - s0a, lenB = s1b - s0b;
    // early independent loads (overlap with gathers)
    bf16x8 zvA = *(const bf16x8*)(z + (size_t)nA * DD + c * 8);
    bf16x8 zvB = *(const bf16x8*)(z + (size_t)(hasB ? nB : nA) * DD + c * 8);
    float brv[8];
#pragma unroll
    for (int q = 0; q < 8; ++q) brv[q] = br[c * 8 + q];

#if USE_FP8
    f32x2 aA[4], aB[4];
#pragma unroll
    for (int q = 0; q < 4; ++q) { aA[q] = (f32x2){0.f, 0.f}; aB[q] = (f32x2){0.f, 0.f}; }
    int jA = s0a + g, jB = s0b + g;
    // fused 4-deep main (both nodes: 8 rows in flight)
    while (jA + 12 < s1a && jB + 12 < s1b) {
        int iA0 = csr[jA], iA1 = csr[jA + 4], iA2 = csr[jA + 8], iA3 = csr[jA + 12];
        int iB0 = csr[jB], iB1 = csr[jB + 4], iB2 = csr[jB + 8], iB3 = csr[jB + 12];
        uint2 vA0 = *(const uint2*)(u + (size_t)iA0 * DD + c * 8);
        uint2 vA1 = *(const uint2*)(u + (size_t)iA1 * DD + c * 8);
        uint2 vA2 = *(const uint2*)(u + (size_t)iA2 * DD + c * 8);
        uint2 vA3 = *(const uint2*)(u + (size_t)iA3 * DD + c * 8);
        uint2 vB0 = *(const uint2*)(u + (size_t)iB0 * DD + c * 8);
        uint2 vB1 = *(const uint2*)(u + (size_t)iB1 * DD + c * 8);
        uint2 vB2 = *(const uint2*)(u + (size_t)iB2 * DD + c * 8);
        uint2 vB3 = *(const uint2*)(u + (size_t)iB3 * DD + c * 8);
        acc_row(aA, vA0); acc_row(aA, vA1); acc_row(aA, vA2); acc_row(aA, vA3);
        acc_row(aB, vB0); acc_row(aB, vB1); acc_row(aB, vB2); acc_row(aB, vB3);
        jA += 16; jB += 16;
    }
    // drains (4-deep single node)
    while (jA + 12 < s1a) {
        int i0 = csr[jA], i1 = csr[jA + 4], i2 = csr[jA + 8], i3 = csr[jA + 12];
        uint2 v0 = *(const uint2*)(u + (size_t)i0 * DD + c * 8);
        uint2 v1 = *(const uint2*)(u + (size_t)i1 * DD + c * 8);
        uint2 v2 = *(const uint2*)(u + (size_t)i2 * DD + c * 8);
        uint2 v3 = *(const uint2*)(u + (size_t)i3 * DD + c * 8);
        acc_row(aA, v0); acc_row(aA, v1); acc_row(aA, v2); acc_row(aA, v3);
        jA += 16;
    }
    while (jB + 12 < s1b) {
        int i0 = csr[jB], i1 = csr[jB + 4], i2 = csr[jB + 8], i3 = csr[jB + 12];
        uint2 v0 = *(const uint2*)(u + (size_t)i0 * DD + c * 8);
        uint2 v1 = *(const uint2*)(u + (size_t)i1 * DD + c * 8);
        uint2 v2 = *(const uint2*)(u + (size_t)i2 * DD + c * 8);
        uint2 v3 = *(const uint2*)(u + (size_t)i3 * DD + c * 8);
        acc_row(aB, v0); acc_row(aB, v1); acc_row(aB, v2); acc_row(aB, v3);
        jB += 16;
    }
    // fused remainders (2 rows in flight)
    while (jA < s1a && jB < s1b) {
        uint2 v0 = *(const uint2*)(u + (size_t)csr[jA] * DD + c * 8);
        uint2 v1 = *(const uint2*)(u + (size_t)csr[jB] * DD + c * 8);
        acc_row(aA, v0); acc_row(aB, v1);
        jA += 4; jB += 4;
    }
    for (; jA < s1a; jA += 4) {
        uint2 v0 = *(const uint2*)(u + (size_t)csr[jA] * DD + c * 8);
        acc_row(aA, v0);
    }
    for (; jB < s1b; jB += 4) {
        uint2 v0 = *(const uint2*)(u + (size_t)csr[jB] * DD + c * 8);
        acc_row(aB, v0);
    }
    float accA[8], accB[8];
#pragma unroll
    for (int q = 0; q < 4; ++q) {
        accA[q * 2] = aA[q].x; accA[q * 2 + 1] = aA[q].y;
        accB[q * 2] = aB[q].x; accB[q * 2 + 1] = aB[q].y;
    }
#else
    const unsigned short* ub16 = (const unsigned short*)u;
    float accA[8], accB[8];
#pragma unroll
    for (int q = 0; q < 8; ++q) { accA[q] = 0.f; accB[q] = 0.f; }
    for (int j = s0a + g; j < s1a; j += 4) {
        bf16x8 v0 = *(const bf16x8*)(ub16 + (size_t)csr[j] * DD + c * 8);
#pragma unroll
        for (int q = 0; q < 8; ++q) accA[q] += bf2f((unsigned short)v0[q]);
    }
    for (int j = s0b + g; j < s1b; j += 4) {
        bf16x8 v0 = *(const bf16x8*)(ub16 + (size_t)csr[j] * DD + c * 8);
#pragma unroll
        for (int q = 0; q < 8; ++q) accB[q] += bf2f((unsigned short)v0[q]);
    }
#endif
#pragma unroll
    for (int q = 0; q < 8; ++q) {
        accA[q] += __shfl_xor(accA[q], 16);
        accA[q] += __shfl_xor(accA[q], 32);
        accB[q] += __shfl_xor(accB[q], 16);
        accB[q] += __shfl_xor(accB[q], 32);
    }
    // ---- epilogue A ----
    {
        float inv = 1.0f / (float)(lenA > 0 ? lenA : 1);
        float bg = lenA > 0 ? 1.f : 0.f;
        float v[8]; float ss = 0.f;
#pragma unroll
        for (int q = 0; q < 8; ++q) {
            v[q] = accA[q] * inv + bf2f((unsigned short)zvA[q]) + bg * brv[q];
            ss = fmaf(v[q], v[q], ss);
        }
        ss += __shfl_xor(ss, 1); ss += __shfl_xor(ss, 2);
        ss += __shfl_xor(ss, 4); ss += __shfl_xor(ss, 8);
        float invn = 1.0f / fmaxf(sqrtf(ss), 1e-12f);
        if (g == 0) {
            bf16x8 r;
#pragma unroll
            for (int q = 0; q < 8; ++q) r[q] = (short)f2bf(fmaxf(v[q], 0.f) * invn);
            *(bf16x8*)(hOut + (size_t)nA * DD + c * 8) = r;
        }
    }
    // ---- epilogue B ----
    if (hasB) {
        float inv = 1.0f / (float)(lenB > 0 ? lenB : 1);
        float bg = lenB > 0 ? 1.f : 0.f;
        float v[8]; float ss = 0.f;
#pragma unroll
        for (int q = 0; q < 8; ++q) {
            v[q] = accB[q] * inv + bf2f((unsigned short)zvB[q]) + bg * brv[q];
            ss = fmaf(v[q], v[q], ss);
        }
        ss += __shfl_xor(ss, 1); ss += __shfl_xor(ss, 2);
        ss += __shfl_xor(ss, 4); ss += __shfl_xor(ss, 8);
        float invn = 1.0f / fmaxf(sqrtf(ss), 1e-12f);
        if (g == 0) {
            bf16x8 r;
#pragma unroll
            for (int q = 0; q < 8; ++q) r[q] = (short)f2bf(fmaxf(v[q], 0.f) * invn);
            *(bf16x8*)(hOut + (size_t)nB * DD + c * 8) = r;
        }
    }
}

// ---------------------------------------------------------------------------
// Pool + tail — unchanged
// ---------------------------------------------------------------------------
__global__ __launch_bounds__(256) void pool_bf16(
    const unsigned short* __restrict__ h, const int* __restrict__ batch,
    float* __restrict__ pooled, float* __restrict__ cnt) {
    int hw = (blockIdx.x * blockDim.x + threadIdx.x) >> 5;
    int lane = threadIdx.x & 31;
    int total_hw = (gridDim.x * blockDim.x) >> 5;
    int chunk = (NN + total_hw - 1) / total_hw;
    int nbeg = hw * chunk;
    int nend = nbeg + chunk; if (nend > NN) nend = NN;
    if (nbeg >= nend) return;
    float ax = 0.f, ay = 0.f, az = 0.f, aw = 0.f;
    int curg = clampi(batch[nbeg], NG);
    int run = 0;
    for (int n = nbeg; n < nend; ++n) {
        int g = clampi(batch[n], NG);
        if (g != curg) {
            atomicAdd(&pooled[curg * DD + lane * 4 + 0], ax);
            atomicAdd(&pooled[curg * DD + lane * 4 + 1], ay);
            atomicAdd(&pooled[curg * DD + lane * 4 + 2], az);
            atomicAdd(&pooled[curg * DD + lane * 4 + 3], aw);
            if (lane == 0) atomicAdd(&cnt[curg], (float)run);
            ax = ay = az = aw = 0.f; run = 0; curg = g;
        }
        const ushort4 v = *(const ushort4*)(h + (size_t)n * DD + lane * 4);
        ax += bf2f(v.x); ay += bf2f(v.y); az += bf2f(v.z); aw += bf2f(v.w);
        ++run;
    }
    atomicAdd(&pooled[curg * DD + lane * 4 + 0], ax);
    atomicAdd(&pooled[curg * DD + lane * 4 + 1], ay);
    atomicAdd(&pooled[curg * DD + lane * 4 + 2], az);
    atomicAdd(&pooled[curg * DD + lane * 4 + 3], aw);
    if (lane == 0) atomicAdd(&cnt[curg], (float)run);
}

__global__ __launch_bounds__(1024) void tail_kernel(
    const float* __restrict__ pooled, const float* __restrict__ cnt,
    const float* __restrict__ W1, const float* __restrict__ b1,
    const float* __restrict__ W2, const float* __restrict__ b2,
    float* __restrict__ out) {
    __shared__ float Wc[16][128];
    __shared__ float bcs[16];
    int t = threadIdx.x;
    for (int i = t; i < 2048; i += 1024) {
        int o = i >> 7, k = i & 127;
        float s = 0.f;
        for (int j = 0; j < 128; ++j) s = fmaf(W2[o * 128 + j], W1[j * 128 + k], s);
        Wc[o][k] = s;
    }
    if (t < 16) {
        float sb = 0.f;
        for (int j = 0; j < 128; ++j) sb = fmaf(W2[t * 128 + j], b1[j], sb);
        bcs[t] = sb + b2[t];
    }
    __syncthreads();
    int g = t >> 4, o = t & 15;
    float invc = 1.0f / fmaxf(cnt[g], 1.0f);
    float z = bcs[o];
    for (int k = 0; k < 128; ++k) z = fmaf(pooled[g * DD + k] * invc, Wc[o][k], z);
    float m = z;
    m = fmaxf(m, __shfl_xor(m, 1)); m = fmaxf(m, __shfl_xor(m, 2));
    m = fmaxf(m, __shfl_xor(m, 4)); m = fmaxf(m, __shfl_xor(m, 8));
    float e = expf(z - m);
    float s = e;
    s += __shfl_xor(s, 1); s += __shfl_xor(s, 2);
    s += __shfl_xor(s, 4); s += __shfl_xor(s, 8);
    out[g * 16 + o] = z - m - logf(s);
}

__global__ void zero_out_kernel(float* __restrict__ out, int n) {
    int i = blockIdx.x * 256 + threadIdx.x;
    if (i < n) out[i] = 0.f;
}

// ---------------------------------------------------------------------------
extern "C" void kernel_launch(void* const* d_in, const int* in_sizes, int n_in,
                              void* d_out, int out_size, void* d_ws, size_t ws_size,
                              hipStream_t stream) {
    const float* x  = (const float*)d_in[0];
    const int*   ei = (const int*)d_in[1];
    const int* batch = (const int*)d_in[2];
    const float* Wl = (const float*)d_in[3];
    const float* bl = (const float*)d_in[4];
    const float* Wr = (const float*)d_in[5];
    const float* br = (const float*)d_in[6];
    const float* W1 = (const float*)d_in[7];
    const float* b1 = (const float*)d_in[8];
    const float* W2 = (const float*)d_in[9];
    const float* b2 = (const float*)d_in[10];
    float* out = (float*)d_out;

    const int* src = ei;          // edge_index[0]
    const int* dst = ei + NE;     // edge_index[1]

    char* ws = (char*)d_ws;
    size_t off = 0;
    auto alloc = [&](size_t bytes) -> void* {
        void* p = ws + off; off += (bytes + 255) & ~(size_t)255; return p;
    };
    unsigned short* hA    = (unsigned short*)alloc((size_t)NN * DD * 2);
    unsigned short* hB    = (unsigned short*)alloc((size_t)NN * DD * 2);
    unsigned short* zb    = (unsigned short*)alloc((size_t)NN * DD * 2);
    unsigned char*  ub    = (unsigned char*)alloc((size_t)NN * DD * 2);
    unsigned short* Wcat3 = (unsigned short*)alloc((size_t)WTOT * 2);
    int* row_ptr  = (int*)alloc((size_t)(NN + 1) * 4);
    int* csr      = (int*)alloc((size_t)NE * 4);
    uint2* stage  = (uint2*)alloc((size_t)NE * 8);
    int* bcnt     = (int*)alloc((size_t)NB * 4);
    int* bstart   = (int*)alloc((size_t)(NB + 1) * 4);
    int* gcur0    = (int*)alloc((size_t)NB * 4);
    float* pooled = (float*)alloc(NG * DD * 4);
    float* cnt    = (float*)alloc(NG * 4);

    if (off > ws_size) {
        zero_out_kernel<<<(out_size + 255) / 256, 256, 0, stream>>>(out, out_size);
        return;
    }

    cvtw_kernel<<<(WTOT + 255) / 256, 256, 0, stream>>>(
        Wl, Wr, Wcat3, bcnt, gcur0, pooled, cnt);

    const int npb = (NE + 7999) / 8000;

    gemm4_kernel<true><<<GB + npb, 256, 0, stream>>>(
        x, Wcat3, bl, zb, ub, dst, bcnt, GB);

    bpart2_kernel<<<npb, 256, 0, stream>>>(src, dst, bcnt, gcur0, bstart, stage);
    bfill_kernel<<<NB, 256, 0, stream>>>(stage, bstart, row_ptr, csr);

    unsigned short* bufs[2] = {hA, hB};
    pullc2_kernel<<<(NN + 7) / 8, 256, 0, stream>>>(
        ub, zb, br, row_ptr, csr, bufs[0]);
    const unsigned short* hin = bufs[0];
    for (int l = 1; l < 3; ++l) {
        gemm4_kernel<false><<<GB, 256, 0, stream>>>(
            hin, Wcat3 + (size_t)l * 32768, bl + (size_t)l * 128,
            zb, ub, dst, bcnt, GB);
        pullc2_kernel<<<(NN + 7) / 8, 256, 0, stream>>>(
            ub, zb, br + (size_t)l * 128, row_ptr, csr, bufs[l & 1]);
        hin = bufs[l & 1];
    }

    pool_bf16<<<256, 256, 0, stream>>>(hin, batch, pooled, cnt);
    tail_kernel<<<1, 1024, 0, stream>>>(pooled, cnt, W1, b1, W2, b2, out);
}

// Round 14
// 364.161 us; speedup vs baseline: 1.2550x; 1.2550x over previous
//
#include <hip/hip_runtime.h>
#include <cstdint>
#include <cstddef>

#define NN 100000   // nodes
#define NE 1600000  // edges
#define DD 128      // feature dim
#define NG 64       // graphs
#define NB 782      // buckets of 128 nodes
#define GB 1563     // gemm blocks: ceil(NN/64)

#if defined(__has_builtin)
#if __has_builtin(__builtin_amdgcn_cvt_pk_f32_fp8) && __has_builtin(__builtin_amdgcn_cvt_pk_fp8_f32)
#define USE_FP8 1
#endif
#endif
#ifndef USE_FP8
#define USE_FP8 0
#endif

using bf16x8 = __attribute__((ext_vector_type(8))) short;
using f32x4  = __attribute__((ext_vector_type(4))) float;
using f32x2  = __attribute__((ext_vector_type(2))) float;

__device__ __forceinline__ int clampi(int v, int hi) {
    v = v < 0 ? 0 : v;
    return v >= hi ? hi - 1 : v;
}
__device__ __forceinline__ unsigned short f2bf(float f) {
    unsigned int u = __float_as_uint(f);
    u += 0x7fffu + ((u >> 16) & 1u);   // RNE
    return (unsigned short)(u >> 16);
}
__device__ __forceinline__ float bf2f(unsigned short s) {
    return __uint_as_float(((unsigned int)s) << 16);
}
#if USE_FP8
__device__ __forceinline__ unsigned char f2fp8(float v) {
    return (unsigned char)(__builtin_amdgcn_cvt_pk_fp8_f32(v, 0.f, 0, false) & 0xFF);
}
__device__ __forceinline__ void acc_row(f32x2* a2, uint2 v) {
    f32x2 p;
    p = __builtin_amdgcn_cvt_pk_f32_fp8(v.x, false); a2[0] += p;
    p = __builtin_amdgcn_cvt_pk_f32_fp8(v.x, true);  a2[1] += p;
    p = __builtin_amdgcn_cvt_pk_f32_fp8(v.y, false); a2[2] += p;
    p = __builtin_amdgcn_cvt_pk_f32_fp8(v.y, true);  a2[3] += p;
}
#endif

// ---------------------------------------------------------------------------
// cvtw: weights -> bf16 Wcat3 in FRAGMENT order (coalesced wave B-loads)
// + zero-init bcnt/gcur0/pooled/cnt.
// ---------------------------------------------------------------------------
#define WTOT (3 * 256 * 128)
__global__ void cvtw_kernel(const float* __restrict__ Wl, const float* __restrict__ Wr,
                            unsigned short* __restrict__ Wcat3,
                            int* __restrict__ bcnt, int* __restrict__ gcur0,
                            float* __restrict__ pooled, float* __restrict__ cnt) {
    int t = blockIdx.x * 256 + threadIdx.x;
    if (t < NB) { bcnt[t] = 0; gcur0[t] = 0; }
    if (t < NG * DD) pooled[t] = 0.f;
    if (t < NG) cnt[t] = 0.f;
    if (t < WTOT) {
        int j    = t & 7;
        int lane = (t >> 3) & 63;
        int ks   = (t >> 9) & 3;
        int n    = (t >> 11) & 7;
        int half = (t >> 14) & 1;
        int l    = t >> 15;
        int l15 = lane & 15, lg = lane >> 4;
        int o = n * 16 + l15;
        int k = ks * 32 + lg * 8 + j;
        const float* Wsrc = half ? Wr : Wl;
        Wcat3[t] = f2bf(Wsrc[(size_t)l * 16384 + o * 128 + k]);
    }
}

// ---------------------------------------------------------------------------
// GEMM v4 (validated round 11): [z|u] = h @ [Wl|Wr]^T, z += bl.
// A via XOR-swizzled LDS; B via fragment-ordered coalesced loads; u -> fp8.
// Extra blocks run the CSR bucket histogram (layer-1 co-launch).
// ---------------------------------------------------------------------------
template <bool F32IN>
__global__ __launch_bounds__(256) void gemm4_kernel(
    const void* __restrict__ hin_, const unsigned short* __restrict__ Wf,
    const float* __restrict__ bl, unsigned short* __restrict__ zb,
    unsigned char* __restrict__ ub, const int* __restrict__ dst,
    int* __restrict__ bcnt, int nG) {
    __shared__ unsigned short lA[64 * 128];
    __shared__ unsigned short sstz[64][136];

    if (blockIdx.x >= nG) {   // bcount branch
        int* lcnt = (int*)lA;
        for (int i = threadIdx.x; i < NB; i += 256) lcnt[i] = 0;
        __syncthreads();
        int b = blockIdx.x - nG;
        int e0 = b * 8000;
        int e1 = e0 + 8000; if (e1 > NE) e1 = NE;
        for (int e = e0 + threadIdx.x; e < e1; e += 256)
            atomicAdd(&lcnt[clampi(dst[e], NN) >> 7], 1);
        __syncthreads();
        for (int i = threadIdx.x; i < NB; i += 256)
            if (lcnt[i]) atomicAdd(&bcnt[i], lcnt[i]);
        return;
    }

    const int tid = threadIdx.x;
    const int w = tid >> 6, l = tid & 63;
    const int l15 = l & 15, lg = l >> 4;
    const int n0 = blockIdx.x * 64;

#pragma unroll
    for (int q = 0; q < 4; ++q) {
        int d = (q * 256 + tid) * 16;
        int row = d >> 8;
        int colb = d & 255;
        int srow = n0 + row; srow = srow < NN ? srow : NN - 1;
        bf16x8 v;
        if (F32IN) {
            const float* rp = (const float*)hin_ + (size_t)srow * DD + (colb >> 1);
            const float4 f0 = *(const float4*)rp;
            const float4 f1 = *(const float4*)(rp + 4);
            v[0] = (short)f2bf(f0.x); v[1] = (short)f2bf(f0.y);
            v[2] = (short)f2bf(f0.z); v[3] = (short)f2bf(f0.w);
            v[4] = (short)f2bf(f1.x); v[5] = (short)f2bf(f1.y);
            v[6] = (short)f2bf(f1.z); v[7] = (short)f2bf(f1.w);
        } else {
            v = *(const bf16x8*)((const unsigned short*)hin_ + (size_t)srow * DD + (colb >> 1));
        }
        int sd = d ^ (((d >> 8) & 7) << 4);
        *(bf16x8*)((char*)lA + sd) = v;
    }
    __syncthreads();

    const int half = w >> 1, rt = w & 1;

    bf16x8 a[4][2];
#pragma unroll
    for (int ks = 0; ks < 4; ++ks)
#pragma unroll
        for (int m = 0; m < 2; ++m) {
            int row = rt * 32 + m * 16 + l15;
            int L = row * 256 + ks * 64 + lg * 16;
            int SL = L ^ (((L >> 8) & 7) << 4);
            a[ks][m] = *(const bf16x8*)((char*)lA + SL);
        }

    f32x4 acc[2][8];
#pragma unroll
    for (int m = 0; m < 2; ++m)
#pragma unroll
        for (int n = 0; n < 8; ++n) acc[m][n] = (f32x4){0.f, 0.f, 0.f, 0.f};

    const unsigned short* Wb = Wf + ((size_t)half << 14);
#pragma unroll
    for (int ks = 0; ks < 4; ++ks) {
#pragma unroll
        for (int n = 0; n < 8; ++n) {
            bf16x8 b = *(const bf16x8*)(Wb + (((n << 2) + ks) << 9) + (l << 3));
            acc[0][n] = __builtin_amdgcn_mfma_f32_16x16x32_bf16(a[ks][0], b, acc[0][n], 0, 0, 0);
            acc[1][n] = __builtin_amdgcn_mfma_f32_16x16x32_bf16(a[ks][1], b, acc[1][n], 0, 0, 0);
        }
    }

    __syncthreads();

    if (half == 0) {
        float blv[8];
#pragma unroll
        for (int n = 0; n < 8; ++n) blv[n] = bl[n * 16 + l15];
#pragma unroll
        for (int m = 0; m < 2; ++m)
#pragma unroll
            for (int r = 0; r < 4; ++r) {
                int brow = rt * 32 + m * 16 + lg * 4 + r;
#pragma unroll
                for (int n = 0; n < 8; ++n)
                    sstz[brow][n * 16 + l15] = f2bf(acc[m][n][r] + blv[n]);
            }
#pragma unroll
        for (int p = 0; p < 8; ++p) {
            int brow = rt * 32 + p * 4 + lg;
            int node = n0 + brow;
            bf16x8 vv = *(const bf16x8*)(&sstz[brow][l15 * 8]);
            if (node < NN)
                *(bf16x8*)(zb + (size_t)node * DD + l15 * 8) = vv;
        }
    } else {
#if USE_FP8
        unsigned char* sstu = (unsigned char*)lA;
#pragma unroll
        for (int m = 0; m < 2; ++m)
#pragma unroll
            for (int r = 0; r < 4; ++r) {
                int brow = rt * 32 + m * 16 + lg * 4 + r;
#pragma unroll
                for (int n = 0; n < 8; ++n)
                    sstu[brow * 136 + n * 16 + l15] = f2fp8(acc[m][n][r]);
            }
        __builtin_amdgcn_s_waitcnt(0);
#pragma unroll
        for (int p = 0; p < 8; ++p) {
            int brow = rt * 32 + p * 4 + lg;
            int node = n0 + brow;
            uint2 vv = *(const uint2*)(sstu + brow * 136 + l15 * 8);
            if (node < NN)
                *(uint2*)(ub + (size_t)node * DD + l15 * 8) = vv;
        }
#else
        unsigned short* ub16 = (unsigned short*)ub;
#pragma unroll
        for (int m = 0; m < 2; ++m)
#pragma unroll
            for (int r = 0; r < 4; ++r) {
                int brow = rt * 32 + m * 16 + lg * 4 + r;
                int node = n0 + brow;
                if (node < NN)
#pragma unroll
                    for (int n = 0; n < 8; ++n)
                        ub16[(size_t)node * DD + n * 16 + l15] = f2bf(acc[m][n][r]);
            }
#endif
    }
}

// ---------------------------------------------------------------------------
// CSR build (unchanged)
// ---------------------------------------------------------------------------
__global__ __launch_bounds__(256) void bpart2_kernel(
    const int* __restrict__ src, const int* __restrict__ dst,
    const int* __restrict__ bcnt, int* __restrict__ gcur0,
    int* __restrict__ bstart_g, uint2* __restrict__ stage) {
    __shared__ int bst[NB];
    __shared__ int lcnt[NB];
    __shared__ int partial[256];
    const int t = threadIdx.x;
    int own[4]; int ssum = 0;
#pragma unroll
    for (int q = 0; q < 4; ++q) {
        int idx = t * 4 + q;
        own[q] = (idx < NB) ? bcnt[idx] : 0;
        ssum += own[q];
    }
    partial[t] = ssum;
    __syncthreads();
    for (int d = 1; d < 256; d <<= 1) {
        int v = (t >= d) ? partial[t - d] : 0;
        __syncthreads();
        partial[t] += v;
        __syncthreads();
    }
    int run = partial[t] - ssum;
#pragma unroll
    for (int q = 0; q < 4; ++q) {
        int idx = t * 4 + q;
        if (idx < NB) bst[idx] = run;
        run += own[q];
    }
    if (blockIdx.x == 0) {
#pragma unroll
        for (int q = 0; q < 4; ++q) {
            int idx = t * 4 + q;
            if (idx < NB) bstart_g[idx] = bst[idx];
        }
        if (t == 0) bstart_g[NB] = NE;
    }
    for (int i = t; i < NB; i += 256) lcnt[i] = 0;
    __syncthreads();
    int e0 = blockIdx.x * 8000;
    int e1 = e0 + 8000; if (e1 > NE) e1 = NE;
    for (int e = e0 + t; e < e1; e += 256)
        atomicAdd(&lcnt[clampi(dst[e], NN) >> 7], 1);
    __syncthreads();
    for (int i = t; i < NB; i += 256) {
        int c = lcnt[i];
        if (c) lcnt[i] = bst[i] + atomicAdd(&gcur0[i], c);
    }
    __syncthreads();
    for (int e = e0 + t; e < e1; e += 256) {
        int d = clampi(dst[e], NN);
        int pos = atomicAdd(&lcnt[d >> 7], 1);
        uint2 p; p.x = (unsigned)clampi(src[e], NN); p.y = (unsigned)d;
        stage[pos] = p;
    }
}

__global__ __launch_bounds__(256) void bfill_kernel(
    const uint2* __restrict__ stage, const int* __restrict__ bstart,
    int* __restrict__ row_ptr, int* __restrict__ csr) {
    __shared__ int scnt[128];
    __shared__ int scur[128];
    const int b = blockIdx.x;
    const int t = threadIdx.x;
    const int s0 = bstart[b], s1 = bstart[b + 1];
    const int n0 = b << 7;
    int nend = NN - n0; if (nend > 128) nend = 128;
    if (t < 128) scnt[t] = 0;
    __syncthreads();
    for (int i = s0 + t; i < s1; i += 256)
        atomicAdd(&scnt[stage[i].y & 127], 1);
    __syncthreads();
    int own = (t < 128) ? scnt[t] : 0;
    for (int d = 1; d < 128; d <<= 1) {
        int v = (t < 128 && t >= d) ? scnt[t - d] : 0;
        __syncthreads();
        if (t < 128) scnt[t] += v;
        __syncthreads();
    }
    if (t < 128) {
        int excl = scnt[t] - own;
        scur[t] = excl;
        if (t < nend) row_ptr[n0 + t] = s0 + excl;
    }
    if (b == NB - 1 && t == 0) row_ptr[NN] = NE;
    __syncthreads();
    for (int i = s0 + t; i < s1; i += 256) {
        uint2 p = stage[i];
        int slot = atomicAdd(&scur[p.y & 127], 1);
        csr[s0 + slot] = (int)p.x;
    }
}

// ---------------------------------------------------------------------------
// Pull + combine v4 (round-10 structure + f32x2 pk accumulation):
// one node per wave, 4 lane-groups of 16, 4-deep ILP, fp8 uint2 row loads.
// h' = relu(normalize(z + mean(u[src]) + [deg>0]*br)) -> bf16
// ---------------------------------------------------------------------------
__global__ __launch_bounds__(256) void pullc3_kernel(
    const unsigned char* __restrict__ u, const unsigned short* __restrict__ z,
    const float* __restrict__ br, const int* __restrict__ row_ptr,
    const int* __restrict__ csr, unsigned short* __restrict__ hOut) {
    int w = threadIdx.x >> 6, lane = threadIdx.x & 63;
    int n = blockIdx.x * 4 + w;
    if (n >= NN) return;
    int g = lane >> 4, c = lane & 15;
    int s0 = row_ptr[n], s1 = row_ptr[n + 1];
    int len = s1 - s0;
    float inv = 1.0f / (float)(len > 0 ? len : 1);
    // hoisted independent loads
    bf16x8 zv = *(const bf16x8*)(z + (size_t)n * DD + c * 8);
#if USE_FP8
    f32x2 a2[4];
#pragma unroll
    for (int q = 0; q < 4; ++q) a2[q] = (f32x2){0.f, 0.f};
    int j = s0 + g;
    for (; j + 12 < s1; j += 16) {
        int i0 = csr[j], i1 = csr[j + 4], i2 = csr[j + 8], i3 = csr[j + 12];
        uint2 v0 = *(const uint2*)(u + (size_t)i0 * DD + c * 8);
        uint2 v1 = *(const uint2*)(u + (size_t)i1 * DD + c * 8);
        uint2 v2 = *(const uint2*)(u + (size_t)i2 * DD + c * 8);
        uint2 v3 = *(const uint2*)(u + (size_t)i3 * DD + c * 8);
        acc_row(a2, v0); acc_row(a2, v1); acc_row(a2, v2); acc_row(a2, v3);
    }
    for (; j < s1; j += 4) {
        uint2 v0 = *(const uint2*)(u + (size_t)csr[j] * DD + c * 8);
        acc_row(a2, v0);
    }
    float acc[8];
#pragma unroll
    for (int q = 0; q < 4; ++q) { acc[q * 2] = a2[q].x; acc[q * 2 + 1] = a2[q].y; }
#else
    const unsigned short* ub16 = (const unsigned short*)u;
    float acc[8];
#pragma unroll
    for (int q = 0; q < 8; ++q) acc[q] = 0.f;
    int j = s0 + g;
    for (; j + 12 < s1; j += 16) {
        int i0 = csr[j], i1 = csr[j + 4], i2 = csr[j + 8], i3 = csr[j + 12];
        bf16x8 v0 = *(const bf16x8*)(ub16 + (size_t)i0 * DD + c * 8);
        bf16x8 v1 = *(const bf16x8*)(ub16 + (size_t)i1 * DD + c * 8);
        bf16x8 v2 = *(const bf16x8*)(ub16 + (size_t)i2 * DD + c * 8);
        bf16x8 v3 = *(const bf16x8*)(ub16 + (size_t)i3 * DD + c * 8);
#pragma unroll
        for (int q = 0; q < 8; ++q)
            acc[q] += (bf2f((unsigned short)v0[q]) + bf2f((unsigned short)v1[q]))
                    + (bf2f((unsigned short)v2[q]) + bf2f((unsigned short)v3[q]));
    }
    for (; j < s1; j += 4) {
        bf16x8 v0 = *(const bf16x8*)(ub16 + (size_t)csr[j] * DD + c * 8);
#pragma unroll
        for (int q = 0; q < 8; ++q) acc[q] += bf2f((unsigned short)v0[q]);
    }
#endif
#pragma unroll
    for (int q = 0; q < 8; ++q) {
        acc[q] += __shfl_xor(acc[q], 16);
        acc[q] += __shfl_xor(acc[q], 32);
    }
    // ---- fused epilogue ----
    const float4 br0 = *(const float4*)(br + c * 8);
    const float4 br1 = *(const float4*)(br + c * 8 + 4);
    float bg = len > 0 ? 1.f : 0.f;
    float v[8]; float ss = 0.f;
#pragma unroll
    for (int q = 0; q < 8; ++q) {
        float brq = (q < 4) ? (&br0.x)[q] : (&br1.x)[q - 4];
        v[q] = acc[q] * inv + bf2f((unsigned short)zv[q]) + bg * brq;
        ss = fmaf(v[q], v[q], ss);
    }
    ss += __shfl_xor(ss, 1); ss += __shfl_xor(ss, 2);
    ss += __shfl_xor(ss, 4); ss += __shfl_xor(ss, 8);
    float invn = 1.0f / fmaxf(sqrtf(ss), 1e-12f);
    if (g == 0) {
        bf16x8 r;
#pragma unroll
        for (int q = 0; q < 8; ++q) r[q] = (short)f2bf(fmaxf(v[q], 0.f) * invn);
        *(bf16x8*)(hOut + (size_t)n * DD + c * 8) = r;
    }
}

// ---------------------------------------------------------------------------
// Pool + tail — unchanged
// ---------------------------------------------------------------------------
__global__ __launch_bounds__(256) void pool_bf16(
    const unsigned short* __restrict__ h, const int* __restrict__ batch,
    float* __restrict__ pooled, float* __restrict__ cnt) {
    int hw = (blockIdx.x * blockDim.x + threadIdx.x) >> 5;
    int lane = threadIdx.x & 31;
    int total_hw = (gridDim.x * blockDim.x) >> 5;
    int chunk = (NN + total_hw - 1) / total_hw;
    int nbeg = hw * chunk;
    int nend = nbeg + chunk; if (nend > NN) nend = NN;
    if (nbeg >= nend) return;
    float ax = 0.f, ay = 0.f, az = 0.f, aw = 0.f;
    int curg = clampi(batch[nbeg], NG);
    int run = 0;
    for (int n = nbeg; n < nend; ++n) {
        int g = clampi(batch[n], NG);
        if (g != curg) {
            atomicAdd(&pooled[curg * DD + lane * 4 + 0], ax);
            atomicAdd(&pooled[curg * DD + lane * 4 + 1], ay);
            atomicAdd(&pooled[curg * DD + lane * 4 + 2], az);
            atomicAdd(&pooled[curg * DD + lane * 4 + 3], aw);
            if (lane == 0) atomicAdd(&cnt[curg], (float)run);
            ax = ay = az = aw = 0.f; run = 0; curg = g;
        }
        const ushort4 v = *(const ushort4*)(h + (size_t)n * DD + lane * 4);
        ax += bf2f(v.x); ay += bf2f(v.y); az += bf2f(v.z); aw += bf2f(v.w);
        ++run;
    }
    atomicAdd(&pooled[curg * DD + lane * 4 + 0], ax);
    atomicAdd(&pooled[curg * DD + lane * 4 + 1], ay);
    atomicAdd(&pooled[curg * DD + lane * 4 + 2], az);
    atomicAdd(&pooled[curg * DD + lane * 4 + 3], aw);
    if (lane == 0) atomicAdd(&cnt[curg], (float)run);
}

__global__ __launch_bounds__(1024) void tail_kernel(
    const float* __restrict__ pooled, const float* __restrict__ cnt,
    const float* __restrict__ W1, const float* __restrict__ b1,
    const float* __restrict__ W2, const float* __restrict__ b2,
    float* __restrict__ out) {
    __shared__ float Wc[16][128];
    __shared__ float bcs[16];
    int t = threadIdx.x;
    for (int i = t; i < 2048; i += 1024) {
        int o = i >> 7, k = i & 127;
        float s = 0.f;
        for (int j = 0; j < 128; ++j) s = fmaf(W2[o * 128 + j], W1[j * 128 + k], s);
        Wc[o][k] = s;
    }
    if (t < 16) {
        float sb = 0.f;
        for (int j = 0; j < 128; ++j) sb = fmaf(W2[t * 128 + j], b1[j], sb);
        bcs[t] = sb + b2[t];
    }
    __syncthreads();
    int g = t >> 4, o = t & 15;
    float invc = 1.0f / fmaxf(cnt[g], 1.0f);
    float z = bcs[o];
    for (int k = 0; k < 128; ++k) z = fmaf(pooled[g * DD + k] * invc, Wc[o][k], z);
    float m = z;
    m = fmaxf(m, __shfl_xor(m, 1)); m = fmaxf(m, __shfl_xor(m, 2));
    m = fmaxf(m, __shfl_xor(m, 4)); m = fmaxf(m, __shfl_xor(m, 8));
    float e = expf(z - m);
    float s = e;
    s += __shfl_xor(s, 1); s += __shfl_xor(s, 2);
    s += __shfl_xor(s, 4); s += __shfl_xor(s, 8);
    out[g * 16 + o] = z - m - logf(s);
}

__global__ void zero_out_kernel(float* __restrict__ out, int n) {
    int i = blockIdx.x * 256 + threadIdx.x;
    if (i < n) out[i] = 0.f;
}

// ---------------------------------------------------------------------------
extern "C" void kernel_launch(void* const* d_in, const int* in_sizes, int n_in,
                              void* d_out, int out_size, void* d_ws, size_t ws_size,
                              hipStream_t stream) {
    const float* x  = (const float*)d_in[0];
    const int*   ei = (const int*)d_in[1];
    const int* batch = (const int*)d_in[2];
    const float* Wl = (const float*)d_in[3];
    const float* bl = (const float*)d_in[4];
    const float* Wr = (const float*)d_in[5];
    const float* br = (const float*)d_in[6];
    const float* W1 = (const float*)d_in[7];
    const float* b1 = (const float*)d_in[8];
    const float* W2 = (const float*)d_in[9];
    const float* b2 = (const float*)d_in[10];
    float* out = (float*)d_out;

    const int* src = ei;          // edge_index[0]
    const int* dst = ei + NE;     // edge_index[1]

    char* ws = (char*)d_ws;
    size_t off = 0;
    auto alloc = [&](size_t bytes) -> void* {
        void* p = ws + off; off += (bytes + 255) & ~(size_t)255; return p;
    };
    unsigned short* hA    = (unsigned short*)alloc((size_t)NN * DD * 2);
    unsigned short* hB    = (unsigned short*)alloc((size_t)NN * DD * 2);
    unsigned short* zb    = (unsigned short*)alloc((size_t)NN * DD * 2);
    unsigned char*  ub    = (unsigned char*)alloc((size_t)NN * DD * 2);
    unsigned short* Wcat3 = (unsigned short*)alloc((size_t)WTOT * 2);
    int* row_ptr  = (int*)alloc((size_t)(NN + 1) * 4);
    int* csr      = (int*)alloc((size_t)NE * 4);
    uint2* stage  = (uint2*)alloc((size_t)NE * 8);
    int* bcnt     = (int*)alloc((size_t)NB * 4);
    int* bstart   = (int*)alloc((size_t)(NB + 1) * 4);
    int* gcur0    = (int*)alloc((size_t)NB * 4);
    float* pooled = (float*)alloc(NG * DD * 4);
    float* cnt    = (float*)alloc(NG * 4);

    if (off > ws_size) {
        zero_out_kernel<<<(out_size + 255) / 256, 256, 0, stream>>>(out, out_size);
        return;
    }

    cvtw_kernel<<<(WTOT + 255) / 256, 256, 0, stream>>>(
        Wl, Wr, Wcat3, bcnt, gcur0, pooled, cnt);

    const int npb = (NE + 7999) / 8000;

    gemm4_kernel<true><<<GB + npb, 256, 0, stream>>>(
        x, Wcat3, bl, zb, ub, dst, bcnt, GB);

    bpart2_kernel<<<npb, 256, 0, stream>>>(src, dst, bcnt, gcur0, bstart, stage);
    bfill_kernel<<<NB, 256, 0, stream>>>(stage, bstart, row_ptr, csr);

    unsigned short* bufs[2] = {hA, hB};
    pullc3_kernel<<<(NN + 3) / 4, 256, 0, stream>>>(
        ub, zb, br, row_ptr, csr, bufs[0]);
    const unsigned short* hin = bufs[0];
    for (int l = 1; l < 3; ++l) {
        gemm4_kernel<false><<<GB, 256, 0, stream>>>(
            hin, Wcat3 + (size_t)l * 32768, bl + (size_t)l * 128,
            zb, ub, dst, bcnt, GB);
        pullc3_kernel<<<(NN + 3) / 4, 256, 0, stream>>>(
            ub, zb, br + (size_t)l * 128, row_ptr, csr, bufs[l & 1]);
        hin = bufs[l & 1];
    }

    pool_bf16<<<256, 256, 0, stream>>>(hin, batch, pooled, cnt);
    tail_kernel<<<1, 1024, 0, stream>>>(pooled, cnt, W1, b1, W2, b2, out);
}

// Round 15
// 350.128 us; speedup vs baseline: 1.3053x; 1.0401x over previous
//
#include <hip/hip_runtime.h>
#include <cstdint>
#include <cstddef>

#define NN 100000   // nodes
#define NE 1600000  // edges
#define DD 128      // feature dim
#define NG 64       // graphs
#define NB 782      // buckets of 128 nodes
#define GB 1563     // gemm blocks: ceil(NN/64)

#if defined(__has_builtin)
#if __has_builtin(__builtin_amdgcn_cvt_pk_f32_fp8) && __has_builtin(__builtin_amdgcn_cvt_pk_fp8_f32)
#define USE_FP8 1
#endif
#endif
#ifndef USE_FP8
#define USE_FP8 0
#endif

using bf16x8 = __attribute__((ext_vector_type(8))) short;
using f32x4  = __attribute__((ext_vector_type(4))) float;
using f32x2  = __attribute__((ext_vector_type(2))) float;

__device__ __forceinline__ int clampi(int v, int hi) {
    v = v < 0 ? 0 : v;
    return v >= hi ? hi - 1 : v;
}
__device__ __forceinline__ unsigned short f2bf(float f) {
    unsigned int u = __float_as_uint(f);
    u += 0x7fffu + ((u >> 16) & 1u);   // RNE
    return (unsigned short)(u >> 16);
}
__device__ __forceinline__ float bf2f(unsigned short s) {
    return __uint_as_float(((unsigned int)s) << 16);
}
#if USE_FP8
__device__ __forceinline__ unsigned char f2fp8(float v) {
    return (unsigned char)(__builtin_amdgcn_cvt_pk_fp8_f32(v, 0.f, 0, false) & 0xFF);
}
__device__ __forceinline__ void acc_row(f32x2* a2, uint2 v) {
    f32x2 p;
    p = __builtin_amdgcn_cvt_pk_f32_fp8(v.x, false); a2[0] += p;
    p = __builtin_amdgcn_cvt_pk_f32_fp8(v.x, true);  a2[1] += p;
    p = __builtin_amdgcn_cvt_pk_f32_fp8(v.y, false); a2[2] += p;
    p = __builtin_amdgcn_cvt_pk_f32_fp8(v.y, true);  a2[3] += p;
}
#endif

// ---------------------------------------------------------------------------
// cvtw: weights -> bf16 Wcat3 in FRAGMENT order (coalesced wave B-loads)
// + zero-init bcnt/gcur0/pooled/cnt.
// ---------------------------------------------------------------------------
#define WTOT (3 * 256 * 128)
__global__ void cvtw_kernel(const float* __restrict__ Wl, const float* __restrict__ Wr,
                            unsigned short* __restrict__ Wcat3,
                            int* __restrict__ bcnt, int* __restrict__ gcur0,
                            float* __restrict__ pooled, float* __restrict__ cnt) {
    int t = blockIdx.x * 256 + threadIdx.x;
    if (t < NB) { bcnt[t] = 0; gcur0[t] = 0; }
    if (t < NG * DD) pooled[t] = 0.f;
    if (t < NG) cnt[t] = 0.f;
    if (t < WTOT) {
        int j    = t & 7;
        int lane = (t >> 3) & 63;
        int ks   = (t >> 9) & 3;
        int n    = (t >> 11) & 7;
        int half = (t >> 14) & 1;
        int l    = t >> 15;
        int l15 = lane & 15, lg = lane >> 4;
        int o = n * 16 + l15;
        int k = ks * 32 + lg * 8 + j;
        const float* Wsrc = half ? Wr : Wl;
        Wcat3[t] = f2bf(Wsrc[(size_t)l * 16384 + o * 128 + k]);
    }
}

// ---------------------------------------------------------------------------
// GEMM v4 (validated round 11): [z|u] = h @ [Wl|Wr]^T, z += bl.
// A via XOR-swizzled LDS; B via fragment-ordered coalesced loads; u -> fp8.
// Extra blocks run the CSR bucket histogram (layer-1 co-launch).
// ---------------------------------------------------------------------------
template <bool F32IN>
__global__ __launch_bounds__(256) void gemm4_kernel(
    const void* __restrict__ hin_, const unsigned short* __restrict__ Wf,
    const float* __restrict__ bl, unsigned short* __restrict__ zb,
    unsigned char* __restrict__ ub, const int* __restrict__ dst,
    int* __restrict__ bcnt, int nG) {
    __shared__ unsigned short lA[64 * 128];
    __shared__ unsigned short sstz[64][136];

    if (blockIdx.x >= nG) {   // bcount branch
        int* lcnt = (int*)lA;
        for (int i = threadIdx.x; i < NB; i += 256) lcnt[i] = 0;
        __syncthreads();
        int b = blockIdx.x - nG;
        int e0 = b * 8000;
        int e1 = e0 + 8000; if (e1 > NE) e1 = NE;
        for (int e = e0 + threadIdx.x; e < e1; e += 256)
            atomicAdd(&lcnt[clampi(dst[e], NN) >> 7], 1);
        __syncthreads();
        for (int i = threadIdx.x; i < NB; i += 256)
            if (lcnt[i]) atomicAdd(&bcnt[i], lcnt[i]);
        return;
    }

    const int tid = threadIdx.x;
    const int w = tid >> 6, l = tid & 63;
    const int l15 = l & 15, lg = l >> 4;
    const int n0 = blockIdx.x * 64;

#pragma unroll
    for (int q = 0; q < 4; ++q) {
        int d = (q * 256 + tid) * 16;
        int row = d >> 8;
        int colb = d & 255;
        int srow = n0 + row; srow = srow < NN ? srow : NN - 1;
        bf16x8 v;
        if (F32IN) {
            const float* rp = (const float*)hin_ + (size_t)srow * DD + (colb >> 1);
            const float4 f0 = *(const float4*)rp;
            const float4 f1 = *(const float4*)(rp + 4);
            v[0] = (short)f2bf(f0.x); v[1] = (short)f2bf(f0.y);
            v[2] = (short)f2bf(f0.z); v[3] = (short)f2bf(f0.w);
            v[4] = (short)f2bf(f1.x); v[5] = (short)f2bf(f1.y);
            v[6] = (short)f2bf(f1.z); v[7] = (short)f2bf(f1.w);
        } else {
            v = *(const bf16x8*)((const unsigned short*)hin_ + (size_t)srow * DD + (colb >> 1));
        }
        int sd = d ^ (((d >> 8) & 7) << 4);
        *(bf16x8*)((char*)lA + sd) = v;
    }
    __syncthreads();

    const int half = w >> 1, rt = w & 1;

    bf16x8 a[4][2];
#pragma unroll
    for (int ks = 0; ks < 4; ++ks)
#pragma unroll
        for (int m = 0; m < 2; ++m) {
            int row = rt * 32 + m * 16 + l15;
            int L = row * 256 + ks * 64 + lg * 16;
            int SL = L ^ (((L >> 8) & 7) << 4);
            a[ks][m] = *(const bf16x8*)((char*)lA + SL);
        }

    f32x4 acc[2][8];
#pragma unroll
    for (int m = 0; m < 2; ++m)
#pragma unroll
        for (int n = 0; n < 8; ++n) acc[m][n] = (f32x4){0.f, 0.f, 0.f, 0.f};

    const unsigned short* Wb = Wf + ((size_t)half << 14);
#pragma unroll
    for (int ks = 0; ks < 4; ++ks) {
#pragma unroll
        for (int n = 0; n < 8; ++n) {
            bf16x8 b = *(const bf16x8*)(Wb + (((n << 2) + ks) << 9) + (l << 3));
            acc[0][n] = __builtin_amdgcn_mfma_f32_16x16x32_bf16(a[ks][0], b, acc[0][n], 0, 0, 0);
            acc[1][n] = __builtin_amdgcn_mfma_f32_16x16x32_bf16(a[ks][1], b, acc[1][n], 0, 0, 0);
        }
    }

    __syncthreads();

    if (half == 0) {
        float blv[8];
#pragma unroll
        for (int n = 0; n < 8; ++n) blv[n] = bl[n * 16 + l15];
#pragma unroll
        for (int m = 0; m < 2; ++m)
#pragma unroll
            for (int r = 0; r < 4; ++r) {
                int brow = rt * 32 + m * 16 + lg * 4 + r;
#pragma unroll
                for (int n = 0; n < 8; ++n)
                    sstz[brow][n * 16 + l15] = f2bf(acc[m][n][r] + blv[n]);
            }
#pragma unroll
        for (int p = 0; p < 8; ++p) {
            int brow = rt * 32 + p * 4 + lg;
            int node = n0 + brow;
            bf16x8 vv = *(const bf16x8*)(&sstz[brow][l15 * 8]);
            if (node < NN)
                *(bf16x8*)(zb + (size_t)node * DD + l15 * 8) = vv;
        }
    } else {
#if USE_FP8
        unsigned char* sstu = (unsigned char*)lA;
#pragma unroll
        for (int m = 0; m < 2; ++m)
#pragma unroll
            for (int r = 0; r < 4; ++r) {
                int brow = rt * 32 + m * 16 + lg * 4 + r;
#pragma unroll
                for (int n = 0; n < 8; ++n)
                    sstu[brow * 136 + n * 16 + l15] = f2fp8(acc[m][n][r]);
            }
        __builtin_amdgcn_s_waitcnt(0);
#pragma unroll
        for (int p = 0; p < 8; ++p) {
            int brow = rt * 32 + p * 4 + lg;
            int node = n0 + brow;
            uint2 vv = *(const uint2*)(sstu + brow * 136 + l15 * 8);
            if (node < NN)
                *(uint2*)(ub + (size_t)node * DD + l15 * 8) = vv;
        }
#else
        unsigned short* ub16 = (unsigned short*)ub;
#pragma unroll
        for (int m = 0; m < 2; ++m)
#pragma unroll
            for (int r = 0; r < 4; ++r) {
                int brow = rt * 32 + m * 16 + lg * 4 + r;
                int node = n0 + brow;
                if (node < NN)
#pragma unroll
                    for (int n = 0; n < 8; ++n)
                        ub16[(size_t)node * DD + n * 16 + l15] = f2bf(acc[m][n][r]);
            }
#endif
    }
}

// ---------------------------------------------------------------------------
// CSR build: stage compressed to uint (src:17 bits | d7:7 bits)
// ---------------------------------------------------------------------------
__global__ __launch_bounds__(256) void bpart2_kernel(
    const int* __restrict__ src, const int* __restrict__ dst,
    const int* __restrict__ bcnt, int* __restrict__ gcur0,
    int* __restrict__ bstart_g, unsigned* __restrict__ stage) {
    __shared__ int bst[NB];
    __shared__ int lcnt[NB];
    __shared__ int partial[256];
    const int t = threadIdx.x;
    int own[4]; int ssum = 0;
#pragma unroll
    for (int q = 0; q < 4; ++q) {
        int idx = t * 4 + q;
        own[q] = (idx < NB) ? bcnt[idx] : 0;
        ssum += own[q];
    }
    partial[t] = ssum;
    __syncthreads();
    for (int d = 1; d < 256; d <<= 1) {
        int v = (t >= d) ? partial[t - d] : 0;
        __syncthreads();
        partial[t] += v;
        __syncthreads();
    }
    int run = partial[t] - ssum;
#pragma unroll
    for (int q = 0; q < 4; ++q) {
        int idx = t * 4 + q;
        if (idx < NB) bst[idx] = run;
        run += own[q];
    }
    if (blockIdx.x == 0) {
#pragma unroll
        for (int q = 0; q < 4; ++q) {
            int idx = t * 4 + q;
            if (idx < NB) bstart_g[idx] = bst[idx];
        }
        if (t == 0) bstart_g[NB] = NE;
    }
    for (int i = t; i < NB; i += 256) lcnt[i] = 0;
    __syncthreads();
    int e0 = blockIdx.x * 8000;
    int e1 = e0 + 8000; if (e1 > NE) e1 = NE;
    for (int e = e0 + t; e < e1; e += 256)
        atomicAdd(&lcnt[clampi(dst[e], NN) >> 7], 1);
    __syncthreads();
    for (int i = t; i < NB; i += 256) {
        int c = lcnt[i];
        if (c) lcnt[i] = bst[i] + atomicAdd(&gcur0[i], c);
    }
    __syncthreads();
    for (int e = e0 + t; e < e1; e += 256) {
        int d = clampi(dst[e], NN);
        int pos = atomicAdd(&lcnt[d >> 7], 1);
        stage[pos] = (unsigned)clampi(src[e], NN) | ((unsigned)(d & 127) << 17);
    }
}

__global__ __launch_bounds__(256) void bfill_kernel(
    const unsigned* __restrict__ stage, const int* __restrict__ bstart,
    int* __restrict__ row_ptr, int* __restrict__ csr) {
    __shared__ int scnt[128];
    __shared__ int scur[128];
    const int b = blockIdx.x;
    const int t = threadIdx.x;
    const int s0 = bstart[b], s1 = bstart[b + 1];
    const int n0 = b << 7;
    int nend = NN - n0; if (nend > 128) nend = 128;
    if (t < 128) scnt[t] = 0;
    __syncthreads();
    for (int i = s0 + t; i < s1; i += 256)
        atomicAdd(&scnt[stage[i] >> 17], 1);
    __syncthreads();
    int own = (t < 128) ? scnt[t] : 0;
    for (int d = 1; d < 128; d <<= 1) {
        int v = (t < 128 && t >= d) ? scnt[t - d] : 0;
        __syncthreads();
        if (t < 128) scnt[t] += v;
        __syncthreads();
    }
    if (t < 128) {
        int excl = scnt[t] - own;
        scur[t] = excl;
        if (t < nend) row_ptr[n0 + t] = s0 + excl;
    }
    if (b == NB - 1 && t == 0) row_ptr[NN] = NE;
    __syncthreads();
    for (int i = s0 + t; i < s1; i += 256) {
        unsigned p = stage[i];
        int slot = atomicAdd(&scur[p >> 17], 1);
        csr[s0 + slot] = (int)(p & 0x1FFFFu);
    }
}

// ---------------------------------------------------------------------------
// Pull + combine v5: one node/wave; ALL neighbor indices captured in ONE
// coalesced wave load (csr[s0+lane], deg<=64 ~always) then shfl-broadcast —
// deletes 3 dependent index-load hops. 16-lane groups, 4-deep, fp8 rows.
// h' = relu(normalize(z + mean(u[src]) + [deg>0]*br)) -> bf16
// ---------------------------------------------------------------------------
__global__ __launch_bounds__(256) void pullc4_kernel(
    const unsigned char* __restrict__ u, const unsigned short* __restrict__ z,
    const float* __restrict__ br, const int* __restrict__ row_ptr,
    const int* __restrict__ csr, unsigned short* __restrict__ hOut) {
    int w = threadIdx.x >> 6, lane = threadIdx.x & 63;
    int n = blockIdx.x * 4 + w;
    if (n >= NN) return;
    int g = lane >> 4, c = lane & 15;
    int s0 = row_ptr[n], s1 = row_ptr[n + 1];
    int len = s1 - s0;
    float inv = 1.0f / (float)(len > 0 ? len : 1);
    // one coalesced index load for the whole neighborhood (deg<=64 path)
    int idxv = (s0 + lane < s1) ? csr[s0 + lane] : 0;
    // hoisted independent loads
    bf16x8 zv = *(const bf16x8*)(z + (size_t)n * DD + c * 8);
#if USE_FP8
    f32x2 a2[4];
#pragma unroll
    for (int q = 0; q < 4; ++q) a2[q] = (f32x2){0.f, 0.f};
    int lcap = len < 64 ? len : 64;
    int r = g;
    for (; r + 12 < lcap; r += 16) {
        int i0 = __shfl(idxv, r);
        int i1 = __shfl(idxv, r + 4);
        int i2 = __shfl(idxv, r + 8);
        int i3 = __shfl(idxv, r + 12);
        uint2 v0 = *(const uint2*)(u + (size_t)i0 * DD + c * 8);
        uint2 v1 = *(const uint2*)(u + (size_t)i1 * DD + c * 8);
        uint2 v2 = *(const uint2*)(u + (size_t)i2 * DD + c * 8);
        uint2 v3 = *(const uint2*)(u + (size_t)i3 * DD + c * 8);
        acc_row(a2, v0); acc_row(a2, v1); acc_row(a2, v2); acc_row(a2, v3);
    }
    for (; r < lcap; r += 4) {
        int i0 = __shfl(idxv, r);
        uint2 v0 = *(const uint2*)(u + (size_t)i0 * DD + c * 8);
        acc_row(a2, v0);
    }
    // rare deg>64 overflow: direct loads
    for (int j = s0 + 64 + g; j < s1; j += 4) {
        uint2 v0 = *(const uint2*)(u + (size_t)csr[j] * DD + c * 8);
        acc_row(a2, v0);
    }
    float acc[8];
#pragma unroll
    for (int q = 0; q < 4; ++q) { acc[q * 2] = a2[q].x; acc[q * 2 + 1] = a2[q].y; }
#else
    const unsigned short* ub16 = (const unsigned short*)u;
    float acc[8];
#pragma unroll
    for (int q = 0; q < 8; ++q) acc[q] = 0.f;
    int lcap = len < 64 ? len : 64;
    int r = g;
    for (; r < lcap; r += 4) {
        int i0 = __shfl(idxv, r);
        bf16x8 v0 = *(const bf16x8*)(ub16 + (size_t)i0 * DD + c * 8);
#pragma unroll
        for (int q = 0; q < 8; ++q) acc[q] += bf2f((unsigned short)v0[q]);
    }
    for (int j = s0 + 64 + g; j < s1; j += 4) {
        bf16x8 v0 = *(const bf16x8*)(ub16 + (size_t)csr[j] * DD + c * 8);
#pragma unroll
        for (int q = 0; q < 8; ++q) acc[q] += bf2f((unsigned short)v0[q]);
    }
#endif
#pragma unroll
    for (int q = 0; q < 8; ++q) {
        acc[q] += __shfl_xor(acc[q], 16);
        acc[q] += __shfl_xor(acc[q], 32);
    }
    // ---- fused epilogue ----
    const float4 br0 = *(const float4*)(br + c * 8);
    const float4 br1 = *(const float4*)(br + c * 8 + 4);
    float bg = len > 0 ? 1.f : 0.f;
    float v[8]; float ss = 0.f;
#pragma unroll
    for (int q = 0; q < 8; ++q) {
        float brq = (q < 4) ? (&br0.x)[q] : (&br1.x)[q - 4];
        v[q] = acc[q] * inv + bf2f((unsigned short)zv[q]) + bg * brq;
        ss = fmaf(v[q], v[q], ss);
    }
    ss += __shfl_xor(ss, 1); ss += __shfl_xor(ss, 2);
    ss += __shfl_xor(ss, 4); ss += __shfl_xor(ss, 8);
    float invn = 1.0f / fmaxf(sqrtf(ss), 1e-12f);
    if (g == 0) {
        bf16x8 rr;
#pragma unroll
        for (int q = 0; q < 8; ++q) rr[q] = (short)f2bf(fmaxf(v[q], 0.f) * invn);
        *(bf16x8*)(hOut + (size_t)n * DD + c * 8) = rr;
    }
}

// ---------------------------------------------------------------------------
// Pool + tail — unchanged
// ---------------------------------------------------------------------------
__global__ __launch_bounds__(256) void pool_bf16(
    const unsigned short* __restrict__ h, const int* __restrict__ batch,
    float* __restrict__ pooled, float* __restrict__ cnt) {
    int hw = (blockIdx.x * blockDim.x + threadIdx.x) >> 5;
    int lane = threadIdx.x & 31;
    int total_hw = (gridDim.x * blockDim.x) >> 5;
    int chunk = (NN + total_hw - 1) / total_hw;
    int nbeg = hw * chunk;
    int nend = nbeg + chunk; if (nend > NN) nend = NN;
    if (nbeg >= nend) return;
    float ax = 0.f, ay = 0.f, az = 0.f, aw = 0.f;
    int curg = clampi(batch[nbeg], NG);
    int run = 0;
    for (int n = nbeg; n < nend; ++n) {
        int g = clampi(batch[n], NG);
        if (g != curg) {
            atomicAdd(&pooled[curg * DD + lane * 4 + 0], ax);
            atomicAdd(&pooled[curg * DD + lane * 4 + 1], ay);
            atomicAdd(&pooled[curg * DD + lane * 4 + 2], az);
            atomicAdd(&pooled[curg * DD + lane * 4 + 3], aw);
            if (lane == 0) atomicAdd(&cnt[curg], (float)run);
            ax = ay = az = aw = 0.f; run = 0; curg = g;
        }
        const ushort4 v = *(const ushort4*)(h + (size_t)n * DD + lane * 4);
        ax += bf2f(v.x); ay += bf2f(v.y); az += bf2f(v.z); aw += bf2f(v.w);
        ++run;
    }
    atomicAdd(&pooled[curg * DD + lane * 4 + 0], ax);
    atomicAdd(&pooled[curg * DD + lane * 4 + 1], ay);
    atomicAdd(&pooled[curg * DD + lane * 4 + 2], az);
    atomicAdd(&pooled[curg * DD + lane * 4 + 3], aw);
    if (lane == 0) atomicAdd(&cnt[curg], (float)run);
}

__global__ __launch_bounds__(1024) void tail_kernel(
    const float* __restrict__ pooled, const float* __restrict__ cnt,
    const float* __restrict__ W1, const float* __restrict__ b1,
    const float* __restrict__ W2, const float* __restrict__ b2,
    float* __restrict__ out) {
    __shared__ float Wc[16][128];
    __shared__ float bcs[16];
    int t = threadIdx.x;
    for (int i = t; i < 2048; i += 1024) {
        int o = i >> 7, k = i & 127;
        float s = 0.f;
        for (int j = 0; j < 128; ++j) s = fmaf(W2[o * 128 + j], W1[j * 128 + k], s);
        Wc[o][k] = s;
    }
    if (t < 16) {
        float sb = 0.f;
        for (int j = 0; j < 128; ++j) sb = fmaf(W2[t * 128 + j], b1[j], sb);
        bcs[t] = sb + b2[t];
    }
    __syncthreads();
    int g = t >> 4, o = t & 15;
    float invc = 1.0f / fmaxf(cnt[g], 1.0f);
    float z = bcs[o];
    for (int k = 0; k < 128; ++k) z = fmaf(pooled[g * DD + k] * invc, Wc[o][k], z);
    float m = z;
    m = fmaxf(m, __shfl_xor(m, 1)); m = fmaxf(m, __shfl_xor(m, 2));
    m = fmaxf(m, __shfl_xor(m, 4)); m = fmaxf(m, __shfl_xor(m, 8));
    float e = expf(z - m);
    float s = e;
    s += __shfl_xor(s, 1); s += __shfl_xor(s, 2);
    s += __shfl_xor(s, 4); s += __shfl_xor(s, 8);
    out[g * 16 + o] = z - m - logf(s);
}

__global__ void zero_out_kernel(float* __restrict__ out, int n) {
    int i = blockIdx.x * 256 + threadIdx.x;
    if (i < n) out[i] = 0.f;
}

// ---------------------------------------------------------------------------
extern "C" void kernel_launch(void* const* d_in, const int* in_sizes, int n_in,
                              void* d_out, int out_size, void* d_ws, size_t ws_size,
                              hipStream_t stream) {
    const float* x  = (const float*)d_in[0];
    const int*   ei = (const int*)d_in[1];
    const int* batch = (const int*)d_in[2];
    const float* Wl = (const float*)d_in[3];
    const float* bl = (const float*)d_in[4];
    const float* Wr = (const float*)d_in[5];
    const float* br = (const float*)d_in[6];
    const float* W1 = (const float*)d_in[7];
    const float* b1 = (const float*)d_in[8];
    const float* W2 = (const float*)d_in[9];
    const float* b2 = (const float*)d_in[10];
    float* out = (float*)d_out;

    const int* src = ei;          // edge_index[0]
    const int* dst = ei + NE;     // edge_index[1]

    char* ws = (char*)d_ws;
    size_t off = 0;
    auto alloc = [&](size_t bytes) -> void* {
        void* p = ws + off; off += (bytes + 255) & ~(size_t)255; return p;
    };
    unsigned short* hA    = (unsigned short*)alloc((size_t)NN * DD * 2);
    unsigned short* hB    = (unsigned short*)alloc((size_t)NN * DD * 2);
    unsigned short* zb    = (unsigned short*)alloc((size_t)NN * DD * 2);
    unsigned char*  ub    = (unsigned char*)alloc((size_t)NN * DD * 2);
    unsigned short* Wcat3 = (unsigned short*)alloc((size_t)WTOT * 2);
    int* row_ptr  = (int*)alloc((size_t)(NN + 1) * 4);
    int* csr      = (int*)alloc((size_t)NE * 4);
    unsigned* stage = (unsigned*)alloc((size_t)NE * 4);
    int* bcnt     = (int*)alloc((size_t)NB * 4);
    int* bstart   = (int*)alloc((size_t)(NB + 1) * 4);
    int* gcur0    = (int*)alloc((size_t)NB * 4);
    float* pooled = (float*)alloc(NG * DD * 4);
    float* cnt    = (float*)alloc(NG * 4);

    if (off > ws_size) {
        zero_out_kernel<<<(out_size + 255) / 256, 256, 0, stream>>>(out, out_size);
        return;
    }

    cvtw_kernel<<<(WTOT + 255) / 256, 256, 0, stream>>>(
        Wl, Wr, Wcat3, bcnt, gcur0, pooled, cnt);

    const int npb = (NE + 7999) / 8000;

    gemm4_kernel<true><<<GB + npb, 256, 0, stream>>>(
        x, Wcat3, bl, zb, ub, dst, bcnt, GB);

    bpart2_kernel<<<npb, 256, 0, stream>>>(src, dst, bcnt, gcur0, bstart, stage);
    bfill_kernel<<<NB, 256, 0, stream>>>(stage, bstart, row_ptr, csr);

    unsigned short* bufs[2] = {hA, hB};
    pullc4_kernel<<<(NN + 3) / 4, 256, 0, stream>>>(
        ub, zb, br, row_ptr, csr, bufs[0]);
    const unsigned short* hin = bufs[0];
    for (int l = 1; l < 3; ++l) {
        gemm4_kernel<false><<<GB, 256, 0, stream>>>(
            hin, Wcat3 + (size_t)l * 32768, bl + (size_t)l * 128,
            zb, ub, dst, bcnt, GB);
        pullc4_kernel<<<(NN + 3) / 4, 256, 0, stream>>>(
            ub, zb, br + (size_t)l * 128, row_ptr, csr, bufs[l & 1]);
        hin = bufs[l & 1];
    }

    pool_bf16<<<256, 256, 0, stream>>>(hin, batch, pooled, cnt);
    tail_kernel<<<1, 1024, 0, stream>>>(pooled, cnt, W1, b1, W2, b2, out);
}

// Round 16
// 344.653 us; speedup vs baseline: 1.3260x; 1.0159x over previous
//
#include <hip/hip_runtime.h>
#include <cstdint>
#include <cstddef>

#define NN 100000   // nodes
#define NE 1600000  // edges
#define DD 128      // feature dim
#define NG 64       // graphs
#define NB 782      // buckets of 128 nodes
#define GB 1563     // gemm blocks: ceil(NN/64)

#if defined(__has_builtin)
#if __has_builtin(__builtin_amdgcn_cvt_pk_f32_fp8) && __has_builtin(__builtin_amdgcn_cvt_pk_fp8_f32)
#define USE_FP8 1
#endif
#endif
#ifndef USE_FP8
#define USE_FP8 0
#endif

using bf16x8 = __attribute__((ext_vector_type(8))) short;
using f32x4  = __attribute__((ext_vector_type(4))) float;
using f32x2  = __attribute__((ext_vector_type(2))) float;

__device__ __forceinline__ int clampi(int v, int hi) {
    v = v < 0 ? 0 : v;
    return v >= hi ? hi - 1 : v;
}
__device__ __forceinline__ unsigned short f2bf(float f) {
    unsigned int u = __float_as_uint(f);
    u += 0x7fffu + ((u >> 16) & 1u);   // RNE
    return (unsigned short)(u >> 16);
}
__device__ __forceinline__ float bf2f(unsigned short s) {
    return __uint_as_float(((unsigned int)s) << 16);
}
#if USE_FP8
__device__ __forceinline__ unsigned char f2fp8(float v) {
    return (unsigned char)(__builtin_amdgcn_cvt_pk_fp8_f32(v, 0.f, 0, false) & 0xFF);
}
__device__ __forceinline__ void acc_row(f32x2* a2, uint2 v) {
    f32x2 p;
    p = __builtin_amdgcn_cvt_pk_f32_fp8(v.x, false); a2[0] += p;
    p = __builtin_amdgcn_cvt_pk_f32_fp8(v.x, true);  a2[1] += p;
    p = __builtin_amdgcn_cvt_pk_f32_fp8(v.y, false); a2[2] += p;
    p = __builtin_amdgcn_cvt_pk_f32_fp8(v.y, true);  a2[3] += p;
}
#endif

// ---------------------------------------------------------------------------
// cvth: weights -> bf16 Wcat3 fragment-order + pooled/cnt zero (blocks <384);
// blocks >= 384 run the CSR bucket histogram (bcnt zeroed by prior memset).
// ---------------------------------------------------------------------------
#define WTOT (3 * 256 * 128)
#define CVB 384   // cvtw blocks (384*256 = WTOT)
__global__ __launch_bounds__(256) void cvth_kernel(
    const float* __restrict__ Wl, const float* __restrict__ Wr,
    unsigned short* __restrict__ Wcat3,
    float* __restrict__ pooled, float* __restrict__ cnt,
    const int* __restrict__ dst, int* __restrict__ bcnt) {
    __shared__ int lcnt[NB];
    if (blockIdx.x >= CVB) {   // hist branch
        for (int i = threadIdx.x; i < NB; i += 256) lcnt[i] = 0;
        __syncthreads();
        int b = blockIdx.x - CVB;
        int e0 = b * 8000;
        int e1 = e0 + 8000; if (e1 > NE) e1 = NE;
        for (int e = e0 + threadIdx.x; e < e1; e += 256)
            atomicAdd(&lcnt[clampi(dst[e], NN) >> 7], 1);
        __syncthreads();
        for (int i = threadIdx.x; i < NB; i += 256)
            if (lcnt[i]) atomicAdd(&bcnt[i], lcnt[i]);
        return;
    }
    int t = blockIdx.x * 256 + threadIdx.x;
    if (t < NG * DD) pooled[t] = 0.f;
    if (t < NG) cnt[t] = 0.f;
    if (t < WTOT) {
        int j    = t & 7;
        int lane = (t >> 3) & 63;
        int ks   = (t >> 9) & 3;
        int n    = (t >> 11) & 7;
        int half = (t >> 14) & 1;
        int l    = t >> 15;
        int l15 = lane & 15, lg = lane >> 4;
        int o = n * 16 + l15;
        int k = ks * 32 + lg * 8 + j;
        const float* Wsrc = half ? Wr : Wl;
        Wcat3[t] = f2bf(Wsrc[(size_t)l * 16384 + o * 128 + k]);
    }
}

// ---------------------------------------------------------------------------
// GEMM v5: [z|u] = h @ [Wl|Wr]^T, z += bl.  512 threads = 8 waves
// (half = w>>2, row-tile rt = w&3; wave: 16 rows x 128 cols, 32 MFMAs).
// Same layouts as validated gemm4: A via XOR-swizzled LDS, B fragment-order,
// u -> fp8. Blocks >= nG run bpart2 (partition + fused bucket scan).
// ---------------------------------------------------------------------------
template <bool F32IN>
__global__ __launch_bounds__(512) void gemm5_kernel(
    const void* __restrict__ hin_, const unsigned short* __restrict__ Wf,
    const float* __restrict__ bl, unsigned short* __restrict__ zb,
    unsigned char* __restrict__ ub,
    const int* __restrict__ src, const int* __restrict__ dst,
    const int* __restrict__ bcnt, int* __restrict__ gcur0,
    int* __restrict__ bstart_g, unsigned* __restrict__ stage, int nG) {
    __shared__ unsigned short lA[64 * 128];    // 16KB
    __shared__ unsigned short sstz[64][136];   // 17.4KB

    if (blockIdx.x >= nG) {   // ---- bpart2 branch (512 threads) ----
        int* bst  = (int*)lA;                    // 782 ints (3128B of 16KB)
        int* lcnt = (int*)(lA + 2048);           // 782 ints at +4KB
        int* partial = (int*)(&sstz[0][0]);      // 512 ints
        const int t = threadIdx.x;
        int own[2]; int ssum = 0;
#pragma unroll
        for (int q = 0; q < 2; ++q) {
            int idx = t * 2 + q;
            own[q] = (idx < NB) ? bcnt[idx] : 0;
            ssum += own[q];
        }
        partial[t] = ssum;
        __syncthreads();
        for (int d = 1; d < 512; d <<= 1) {
            int v = (t >= d) ? partial[t - d] : 0;
            __syncthreads();
            partial[t] += v;
            __syncthreads();
        }
        int run = partial[t] - ssum;
#pragma unroll
        for (int q = 0; q < 2; ++q) {
            int idx = t * 2 + q;
            if (idx < NB) bst[idx] = run;
            run += own[q];
        }
        if (blockIdx.x == nG) {
#pragma unroll
            for (int q = 0; q < 2; ++q) {
                int idx = t * 2 + q;
                if (idx < NB) bstart_g[idx] = bst[idx];
            }
            if (t == 0) bstart_g[NB] = NE;
        }
        for (int i = t; i < NB; i += 512) lcnt[i] = 0;
        __syncthreads();
        int b = blockIdx.x - nG;
        int e0 = b * 8000;
        int e1 = e0 + 8000; if (e1 > NE) e1 = NE;
        for (int e = e0 + t; e < e1; e += 512)
            atomicAdd(&lcnt[clampi(dst[e], NN) >> 7], 1);
        __syncthreads();
        for (int i = t; i < NB; i += 512) {
            int c = lcnt[i];
            if (c) lcnt[i] = bst[i] + atomicAdd(&gcur0[i], c);
        }
        __syncthreads();
        for (int e = e0 + t; e < e1; e += 512) {
            int d = clampi(dst[e], NN);
            int pos = atomicAdd(&lcnt[d >> 7], 1);
            stage[pos] = (unsigned)clampi(src[e], NN) | ((unsigned)(d & 127) << 17);
        }
        return;
    }

    // ---- gemm branch ----
    const int tid = threadIdx.x;
    const int w = tid >> 6, l = tid & 63;
    const int l15 = l & 15, lg = l >> 4;
    const int n0 = blockIdx.x * 64;

    // stage A: linear global -> swizzled LDS (1024 x 16B over 2 iters)
#pragma unroll
    for (int q = 0; q < 2; ++q) {
        int d = (q * 512 + tid) * 16;
        int row = d >> 8;
        int colb = d & 255;
        int srow = n0 + row; srow = srow < NN ? srow : NN - 1;
        bf16x8 v;
        if (F32IN) {
            const float* rp = (const float*)hin_ + (size_t)srow * DD + (colb >> 1);
            const float4 f0 = *(const float4*)rp;
            const float4 f1 = *(const float4*)(rp + 4);
            v[0] = (short)f2bf(f0.x); v[1] = (short)f2bf(f0.y);
            v[2] = (short)f2bf(f0.z); v[3] = (short)f2bf(f0.w);
            v[4] = (short)f2bf(f1.x); v[5] = (short)f2bf(f1.y);
            v[6] = (short)f2bf(f1.z); v[7] = (short)f2bf(f1.w);
        } else {
            v = *(const bf16x8*)((const unsigned short*)hin_ + (size_t)srow * DD + (colb >> 1));
        }
        int sd = d ^ (((d >> 8) & 7) << 4);
        *(bf16x8*)((char*)lA + sd) = v;
    }
    __syncthreads();

    const int half = w >> 2, rt = w & 3;

    // A fragments (16 rows per wave) from swizzled LDS
    bf16x8 a[4];
#pragma unroll
    for (int ks = 0; ks < 4; ++ks) {
        int row = rt * 16 + l15;
        int L = row * 256 + ks * 64 + lg * 16;
        int SL = L ^ (((L >> 8) & 7) << 4);
        a[ks] = *(const bf16x8*)((char*)lA + SL);
    }

    f32x4 acc[8];
#pragma unroll
    for (int n = 0; n < 8; ++n) acc[n] = (f32x4){0.f, 0.f, 0.f, 0.f};

    const unsigned short* Wb = Wf + ((size_t)half << 14);
#pragma unroll
    for (int ks = 0; ks < 4; ++ks) {
#pragma unroll
        for (int n = 0; n < 8; ++n) {
            bf16x8 b = *(const bf16x8*)(Wb + (((n << 2) + ks) << 9) + (l << 3));
            acc[n] = __builtin_amdgcn_mfma_f32_16x16x32_bf16(a[ks], b, acc[n], 0, 0, 0);
        }
    }

    __syncthreads();   // lA reads complete before u-repack reuses lA

    if (half == 0) {   // z: bias + bf16 repack + coalesced stores
        float blv[8];
#pragma unroll
        for (int n = 0; n < 8; ++n) blv[n] = bl[n * 16 + l15];
#pragma unroll
        for (int r = 0; r < 4; ++r) {
            int brow = rt * 16 + lg * 4 + r;
#pragma unroll
            for (int n = 0; n < 8; ++n)
                sstz[brow][n * 16 + l15] = f2bf(acc[n][r] + blv[n]);
        }
#pragma unroll
        for (int p = 0; p < 4; ++p) {
            int brow = rt * 16 + p * 4 + lg;
            int node = n0 + brow;
            bf16x8 vv = *(const bf16x8*)(&sstz[brow][l15 * 8]);
            if (node < NN)
                *(bf16x8*)(zb + (size_t)node * DD + l15 * 8) = vv;
        }
    } else {           // u: fp8 repack (reuses lA) + coalesced stores
#if USE_FP8
        unsigned char* sstu = (unsigned char*)lA;   // 64 x 136B
#pragma unroll
        for (int r = 0; r < 4; ++r) {
            int brow = rt * 16 + lg * 4 + r;
#pragma unroll
            for (int n = 0; n < 8; ++n)
                sstu[brow * 136 + n * 16 + l15] = f2fp8(acc[n][r]);
        }
        __builtin_amdgcn_s_waitcnt(0);
#pragma unroll
        for (int p = 0; p < 4; ++p) {
            int brow = rt * 16 + p * 4 + lg;
            int node = n0 + brow;
            uint2 vv = *(const uint2*)(sstu + brow * 136 + l15 * 8);
            if (node < NN)
                *(uint2*)(ub + (size_t)node * DD + l15 * 8) = vv;
        }
#else
        unsigned short* ub16 = (unsigned short*)ub;
#pragma unroll
        for (int r = 0; r < 4; ++r) {
            int brow = rt * 16 + lg * 4 + r;
            int node = n0 + brow;
            if (node < NN)
#pragma unroll
                for (int n = 0; n < 8; ++n)
                    ub16[(size_t)node * DD + n * 16 + l15] = f2bf(acc[n][r]);
        }
#endif
    }
}

// ---------------------------------------------------------------------------
// bfill: per-bucket degree count -> scan -> row_ptr + dense csr (unchanged)
// ---------------------------------------------------------------------------
__global__ __launch_bounds__(256) void bfill_kernel(
    const unsigned* __restrict__ stage, const int* __restrict__ bstart,
    int* __restrict__ row_ptr, int* __restrict__ csr) {
    __shared__ int scnt[128];
    __shared__ int scur[128];
    const int b = blockIdx.x;
    const int t = threadIdx.x;
    const int s0 = bstart[b], s1 = bstart[b + 1];
    const int n0 = b << 7;
    int nend = NN - n0; if (nend > 128) nend = 128;
    if (t < 128) scnt[t] = 0;
    __syncthreads();
    for (int i = s0 + t; i < s1; i += 256)
        atomicAdd(&scnt[stage[i] >> 17], 1);
    __syncthreads();
    int own = (t < 128) ? scnt[t] : 0;
    for (int d = 1; d < 128; d <<= 1) {
        int v = (t < 128 && t >= d) ? scnt[t - d] : 0;
        __syncthreads();
        if (t < 128) scnt[t] += v;
        __syncthreads();
    }
    if (t < 128) {
        int excl = scnt[t] - own;
        scur[t] = excl;
        if (t < nend) row_ptr[n0 + t] = s0 + excl;
    }
    if (b == NB - 1 && t == 0) row_ptr[NN] = NE;
    __syncthreads();
    for (int i = s0 + t; i < s1; i += 256) {
        unsigned p = stage[i];
        int slot = atomicAdd(&scur[p >> 17], 1);
        csr[s0 + slot] = (int)(p & 0x1FFFFu);
    }
}

// ---------------------------------------------------------------------------
// Pull + combine v5 (validated round 15): one node/wave; whole neighborhood's
// indices in ONE coalesced wave load + shfl broadcast; 16-lane groups, 4-deep,
// fp8 rows. h' = relu(normalize(z + mean(u[src]) + [deg>0]*br)) -> bf16
// ---------------------------------------------------------------------------
__global__ __launch_bounds__(256) void pullc4_kernel(
    const unsigned char* __restrict__ u, const unsigned short* __restrict__ z,
    const float* __restrict__ br, const int* __restrict__ row_ptr,
    const int* __restrict__ csr, unsigned short* __restrict__ hOut) {
    int w = threadIdx.x >> 6, lane = threadIdx.x & 63;
    int n = blockIdx.x * 4 + w;
    if (n >= NN) return;
    int g = lane >> 4, c = lane & 15;
    int s0 = row_ptr[n], s1 = row_ptr[n + 1];
    int len = s1 - s0;
    float inv = 1.0f / (float)(len > 0 ? len : 1);
    int idxv = (s0 + lane < s1) ? csr[s0 + lane] : 0;
    bf16x8 zv = *(const bf16x8*)(z + (size_t)n * DD + c * 8);
#if USE_FP8
    f32x2 a2[4];
#pragma unroll
    for (int q = 0; q < 4; ++q) a2[q] = (f32x2){0.f, 0.f};
    int lcap = len < 64 ? len : 64;
    int r = g;
    for (; r + 12 < lcap; r += 16) {
        int i0 = __shfl(idxv, r);
        int i1 = __shfl(idxv, r + 4);
        int i2 = __shfl(idxv, r + 8);
        int i3 = __shfl(idxv, r + 12);
        uint2 v0 = *(const uint2*)(u + (size_t)i0 * DD + c * 8);
        uint2 v1 = *(const uint2*)(u + (size_t)i1 * DD + c * 8);
        uint2 v2 = *(const uint2*)(u + (size_t)i2 * DD + c * 8);
        uint2 v3 = *(const uint2*)(u + (size_t)i3 * DD + c * 8);
        acc_row(a2, v0); acc_row(a2, v1); acc_row(a2, v2); acc_row(a2, v3);
    }
    for (; r < lcap; r += 4) {
        int i0 = __shfl(idxv, r);
        uint2 v0 = *(const uint2*)(u + (size_t)i0 * DD + c * 8);
        acc_row(a2, v0);
    }
    for (int j = s0 + 64 + g; j < s1; j += 4) {
        uint2 v0 = *(const uint2*)(u + (size_t)csr[j] * DD + c * 8);
        acc_row(a2, v0);
    }
    float acc[8];
#pragma unroll
    for (int q = 0; q < 4; ++q) { acc[q * 2] = a2[q].x; acc[q * 2 + 1] = a2[q].y; }
#else
    const unsigned short* ub16 = (const unsigned short*)u;
    float acc[8];
#pragma unroll
    for (int q = 0; q < 8; ++q) acc[q] = 0.f;
    int lcap = len < 64 ? len : 64;
    int r = g;
    for (; r < lcap; r += 4) {
        int i0 = __shfl(idxv, r);
        bf16x8 v0 = *(const bf16x8*)(ub16 + (size_t)i0 * DD + c * 8);
#pragma unroll
        for (int q = 0; q < 8; ++q) acc[q] += bf2f((unsigned short)v0[q]);
    }
    for (int j = s0 + 64 + g; j < s1; j += 4) {
        bf16x8 v0 = *(const bf16x8*)(ub16 + (size_t)csr[j] * DD + c * 8);
#pragma unroll
        for (int q = 0; q < 8; ++q) acc[q] += bf2f((unsigned short)v0[q]);
    }
#endif
#pragma unroll
    for (int q = 0; q < 8; ++q) {
        acc[q] += __shfl_xor(acc[q], 16);
        acc[q] += __shfl_xor(acc[q], 32);
    }
    const float4 br0 = *(const float4*)(br + c * 8);
    const float4 br1 = *(const float4*)(br + c * 8 + 4);
    float bg = len > 0 ? 1.f : 0.f;
    float v[8]; float ss = 0.f;
#pragma unroll
    for (int q = 0; q < 8; ++q) {
        float brq = (q < 4) ? (&br0.x)[q] : (&br1.x)[q - 4];
        v[q] = acc[q] * inv + bf2f((unsigned short)zv[q]) + bg * brq;
        ss = fmaf(v[q], v[q], ss);
    }
    ss += __shfl_xor(ss, 1); ss += __shfl_xor(ss, 2);
    ss += __shfl_xor(ss, 4); ss += __shfl_xor(ss, 8);
    float invn = 1.0f / fmaxf(sqrtf(ss), 1e-12f);
    if (g == 0) {
        bf16x8 rr;
#pragma unroll
        for (int q = 0; q < 8; ++q) rr[q] = (short)f2bf(fmaxf(v[q], 0.f) * invn);
        *(bf16x8*)(hOut + (size_t)n * DD + c * 8) = rr;
    }
}

// ---------------------------------------------------------------------------
// Pool + tail — unchanged
// ---------------------------------------------------------------------------
__global__ __launch_bounds__(256) void pool_bf16(
    const unsigned short* __restrict__ h, const int* __restrict__ batch,
    float* __restrict__ pooled, float* __restrict__ cnt) {
    int hw = (blockIdx.x * blockDim.x + threadIdx.x) >> 5;
    int lane = threadIdx.x & 31;
    int total_hw = (gridDim.x * blockDim.x) >> 5;
    int chunk = (NN + total_hw - 1) / total_hw;
    int nbeg = hw * chunk;
    int nend = nbeg + chunk; if (nend > NN) nend = NN;
    if (nbeg >= nend) return;
    float ax = 0.f, ay = 0.f, az = 0.f, aw = 0.f;
    int curg = clampi(batch[nbeg], NG);
    int run = 0;
    for (int n = nbeg; n < nend; ++n) {
        int g = clampi(batch[n], NG);
        if (g != curg) {
            atomicAdd(&pooled[curg * DD + lane * 4 + 0], ax);
            atomicAdd(&pooled[curg * DD + lane * 4 + 1], ay);
            atomicAdd(&pooled[curg * DD + lane * 4 + 2], az);
            atomicAdd(&pooled[curg * DD + lane * 4 + 3], aw);
            if (lane == 0) atomicAdd(&cnt[curg], (float)run);
            ax = ay = az = aw = 0.f; run = 0; curg = g;
        }
        const ushort4 v = *(const ushort4*)(h + (size_t)n * DD + lane * 4);
        ax += bf2f(v.x); ay += bf2f(v.y); az += bf2f(v.z); aw += bf2f(v.w);
        ++run;
    }
    atomicAdd(&pooled[curg * DD + lane * 4 + 0], ax);
    atomicAdd(&pooled[curg * DD + lane * 4 + 1], ay);
    atomicAdd(&pooled[curg * DD + lane * 4 + 2], az);
    atomicAdd(&pooled[curg * DD + lane * 4 + 3], aw);
    if (lane == 0) atomicAdd(&cnt[curg], (float)run);
}

__global__ __launch_bounds__(1024) void tail_kernel(
    const float* __restrict__ pooled, const float* __restrict__ cnt,
    const float* __restrict__ W1, const float* __restrict__ b1,
    const float* __restrict__ W2, const float* __restrict__ b2,
    float* __restrict__ out) {
    __shared__ float Wc[16][128];
    __shared__ float bcs[16];
    int t = threadIdx.x;
    for (int i = t; i < 2048; i += 1024) {
        int o = i >> 7, k = i & 127;
        float s = 0.f;
        for (int j = 0; j < 128; ++j) s = fmaf(W2[o * 128 + j], W1[j * 128 + k], s);
        Wc[o][k] = s;
    }
    if (t < 16) {
        float sb = 0.f;
        for (int j = 0; j < 128; ++j) sb = fmaf(W2[t * 128 + j], b1[j], sb);
        bcs[t] = sb + b2[t];
    }
    __syncthreads();
    int g = t >> 4, o = t & 15;
    float invc = 1.0f / fmaxf(cnt[g], 1.0f);
    float z = bcs[o];
    for (int k = 0; k < 128; ++k) z = fmaf(pooled[g * DD + k] * invc, Wc[o][k], z);
    float m = z;
    m = fmaxf(m, __shfl_xor(m, 1)); m = fmaxf(m, __shfl_xor(m, 2));
    m = fmaxf(m, __shfl_xor(m, 4)); m = fmaxf(m, __shfl_xor(m, 8));
    float e = expf(z - m);
    float s = e;
    s += __shfl_xor(s, 1); s += __shfl_xor(s, 2);
    s += __shfl_xor(s, 4); s += __shfl_xor(s, 8);
    out[g * 16 + o] = z - m - logf(s);
}

__global__ void zero_out_kernel(float* __restrict__ out, int n) {
    int i = blockIdx.x * 256 + threadIdx.x;
    if (i < n) out[i] = 0.f;
}

// ---------------------------------------------------------------------------
extern "C" void kernel_launch(void* const* d_in, const int* in_sizes, int n_in,
                              void* d_out, int out_size, void* d_ws, size_t ws_size,
                              hipStream_t stream) {
    const float* x  = (const float*)d_in[0];
    const int*   ei = (const int*)d_in[1];
    const int* batch = (const int*)d_in[2];
    const float* Wl = (const float*)d_in[3];
    const float* bl = (const float*)d_in[4];
    const float* Wr = (const float*)d_in[5];
    const float* br = (const float*)d_in[6];
    const float* W1 = (const float*)d_in[7];
    const float* b1 = (const float*)d_in[8];
    const float* W2 = (const float*)d_in[9];
    const float* b2 = (const float*)d_in[10];
    float* out = (float*)d_out;

    const int* src = ei;          // edge_index[0]
    const int* dst = ei + NE;     // edge_index[1]

    char* ws = (char*)d_ws;
    size_t off = 0;
    auto alloc = [&](size_t bytes) -> void* {
        void* p = ws + off; off += (bytes + 255) & ~(size_t)255; return p;
    };
    unsigned short* hA    = (unsigned short*)alloc((size_t)NN * DD * 2);
    unsigned short* hB    = (unsigned short*)alloc((size_t)NN * DD * 2);
    unsigned short* zb    = (unsigned short*)alloc((size_t)NN * DD * 2);
    unsigned char*  ub    = (unsigned char*)alloc((size_t)NN * DD * 2);
    unsigned short* Wcat3 = (unsigned short*)alloc((size_t)WTOT * 2);
    int* row_ptr  = (int*)alloc((size_t)(NN + 1) * 4);
    int* csr      = (int*)alloc((size_t)NE * 4);
    unsigned* stage = (unsigned*)alloc((size_t)NE * 4);
    int* bcnt     = (int*)alloc((size_t)NB * 4);   // adjacent: one memset
    int* gcur0    = (int*)alloc((size_t)NB * 4);   // covers bcnt+gcur0
    int* bstart   = (int*)alloc((size_t)(NB + 1) * 4);
    float* pooled = (float*)alloc(NG * DD * 4);
    float* cnt    = (float*)alloc(NG * 4);

    if (off > ws_size) {
        zero_out_kernel<<<(out_size + 255) / 256, 256, 0, stream>>>(out, out_size);
        return;
    }

    const int npb = (NE + 7999) / 8000;   // 200

    // zero bcnt+gcur0 (adjacent, padded) in one async memset
    size_t bc_pad = ((size_t)NB * 4 + 255) & ~(size_t)255;
    hipMemsetAsync(bcnt, 0, bc_pad * 2, stream);

    // weight convert + pooled/cnt zero, co-launched with CSR histogram
    cvth_kernel<<<CVB + npb, 256, 0, stream>>>(Wl, Wr, Wcat3, pooled, cnt, dst, bcnt);

    // layer-1 GEMM (f32 x) co-launched with bpart2 (partition + fused scan)
    gemm5_kernel<true><<<GB + npb, 512, 0, stream>>>(
        x, Wcat3, bl, zb, ub, src, dst, bcnt, gcur0, bstart, stage, GB);

    bfill_kernel<<<NB, 256, 0, stream>>>(stage, bstart, row_ptr, csr);

    unsigned short* bufs[2] = {hA, hB};
    pullc4_kernel<<<(NN + 3) / 4, 256, 0, stream>>>(
        ub, zb, br, row_ptr, csr, bufs[0]);
    const unsigned short* hin = bufs[0];
    for (int l = 1; l < 3; ++l) {
        gemm5_kernel<false><<<GB, 512, 0, stream>>>(
            hin, Wcat3 + (size_t)l * 32768, bl + (size_t)l * 128,
            zb, ub, src, dst, bcnt, gcur0, bstart, stage, GB);
        pullc4_kernel<<<(NN + 3) / 4, 256, 0, stream>>>(
            ub, zb, br + (size_t)l * 128, row_ptr, csr, bufs[l & 1]);
        hin = bufs[l & 1];
    }

    pool_bf16<<<256, 256, 0, stream>>>(hin, batch, pooled, cnt);
    tail_kernel<<<1, 1024, 0, stream>>>(pooled, cnt, W1, b1, W2, b2, out);
}